// Round 3
// baseline (683.655 us; speedup 1.0000x reference)
//
#include <hip/hip_runtime.h>
#include <cstdint>

typedef __attribute__((ext_vector_type(8))) short short8;
typedef __attribute__((ext_vector_type(16))) float f32x16;

#define B_   32
#define IN_  2048
#define ID_  16
#define ON_  64
#define OD_  32
// weight strides (floats): o: 1048576, i: 512, d: 16, k: 1

__device__ __forceinline__ unsigned short f2bf(float f) {
    union { float f; uint32_t u; } c; c.f = f;
    uint32_t u = c.u;
    uint32_t r = (u + 0x7FFFu + ((u >> 16) & 1u)) >> 16;
    return (unsigned short)r;
}
__device__ __forceinline__ unsigned int pack2(float a, float b) {
    return (unsigned int)f2bf(a) | ((unsigned int)f2bf(b) << 16);
}

// ============================ FAST PATH =====================================
// ws layout:
//   wbf  : bf16 weight in MFMA B-fragment order, uint4[(o*2048+i)*64 + lane]   134,217,728 B
//   xbf  : bf16 x in MFMA A-fragment order,      uint4[i*64 + lane]              2,097,152 B
//   part : fp32 partials [slice][b*2048+o*32+d]                                 67,108,864 B
//   v0, vsum : fp32 [o][b][d]                                                     262,144 B each

// ---- pack x -> A-fragment layout: lane holds x[b=lane&31, i, k=half*8+j] ----
__global__ __launch_bounds__(256) void xconv_k(
    const float* __restrict__ x, uint4* __restrict__ xbf)
{
    int t = threadIdx.x, lane = t & 63, wv = t >> 6;
    int i = blockIdx.x * 4 + wv;
    int b = lane & 31, half = lane >> 5;
    const float* g = x + ((size_t)b * IN_ + i) * ID_ + half * 8;
    float4 a = *(const float4*)g;
    float4 c = *(const float4*)(g + 4);
    uint4 p = { pack2(a.x, a.y), pack2(a.z, a.w), pack2(c.x, c.y), pack2(c.z, c.w) };
    xbf[(size_t)i * 64 + lane] = p;
}

// ---- pass0: read w fp32 direct->reg, emit wbf, MFMA-accumulate S0 partials --
// grid 256 = 64 ic (i-chunk 32) x 4 og (16 o). block 1024 = 16 waves x 1 o.
// launch_bounds(1024,4): 16 waves/block = 4 waves/SIMD -> 128-VGPR budget (no spills)
__global__ __launch_bounds__(1024, 4) void pass0_k2(
    const float* __restrict__ w, const uint4* __restrict__ xbf,
    uint4* __restrict__ wbf, float* __restrict__ part)
{
    int t = threadIdx.x, lane = t & 63, wv = t >> 6;
    int og = blockIdx.x & 3, ic = blockIdx.x >> 2;
    int o = og * 16 + wv;
    int d = lane & 31, half = lane >> 5;

    f32x16 acc = {};
    #pragma unroll 4
    for (int ii = 0; ii < 32; ++ii) {
        int i = ic * 32 + ii;
        union { uint4 u; short8 s; } af;
        af.u = xbf[(size_t)i * 64 + lane];
        const float* g = w + ((size_t)o * IN_ + i) * 512 + d * 16 + half * 8;
        float4 a = *(const float4*)g;
        float4 c = *(const float4*)(g + 4);
        union { uint4 u; short8 s; } bf;
        bf.u = (uint4){ pack2(a.x, a.y), pack2(a.z, a.w), pack2(c.x, c.y), pack2(c.z, c.w) };
        wbf[((size_t)o * IN_ + i) * 64 + lane] = bf.u;
        acc = __builtin_amdgcn_mfma_f32_32x32x16_bf16(af.s, bf.s, acc, 0, 0, 0);
    }
    float* dst = part + (size_t)ic * 65536;
    #pragma unroll
    for (int r = 0; r < 16; ++r) {
        int b = (r & 3) + 8 * (r >> 2) + 4 * half;
        dst[(size_t)b * 2048 + o * 32 + d] = acc[r];
    }
}

// ---- routing pass: weight frags direct global->reg, softmax via 16 KB LDS --
// grid 256 ic (i-chunk 8). block 1024 = 16 waves x 4 o. 4 waves/SIMD, 128 VGPR.
// Phase B re-loads wbf (L2-hit) instead of keeping fragments live -> no spill.
__global__ __launch_bounds__(1024, 4) void route_k2(
    const uint4* __restrict__ wbf, const uint4* __restrict__ xbf,
    const float* __restrict__ vin /*[o][b][d]*/, float* __restrict__ part)
{
    __shared__ float blds[B_ * ON_];
    __shared__ float clds[B_ * ON_];

    int t = threadIdx.x, lane = t & 63, wv = t >> 6;
    int ic = blockIdx.x;
    int d = lane & 31, half = lane >> 5;

    f32x16 acc[4] = {};

    for (int ii = 0; ii < 8; ++ii) {
        int i = ic * 8 + ii;
        union { uint4 u; short8 s; } af;
        af.u = xbf[(size_t)i * 64 + lane];

        // phase A: logits b[b,o] = dot_d(v[b,o,:], xhat[b,o,i,:])
        #pragma unroll
        for (int oi = 0; oi < 4; ++oi) {
            int o = wv * 4 + oi;
            union { uint4 u; short8 s; } bb;
            bb.u = wbf[((size_t)o * IN_ + i) * 64 + lane];
            f32x16 z = {};
            f32x16 C = __builtin_amdgcn_mfma_f32_32x32x16_bf16(af.s, bb.s, z, 0, 0, 0);
            const float* vp = vin + (size_t)o * (B_ * OD_) + d;
            #pragma unroll
            for (int r = 0; r < 16; ++r) {
                int b = (r & 3) + 8 * (r >> 2) + 4 * half;
                C[r] *= vp[b * 32];
            }
            #pragma unroll
            for (int m = 1; m <= 16; m <<= 1) {
                #pragma unroll
                for (int r = 0; r < 16; ++r) C[r] += __shfl_xor(C[r], m, 32);
            }
            if ((lane & 31) == 0) {
                #pragma unroll
                for (int r = 0; r < 16; ++r) {
                    int b = (r & 3) + 8 * (r >> 2) + 4 * half;
                    blds[b * ON_ + o] = C[r];
                }
            }
        }
        __syncthreads();

        // softmax over o for each b: 1024 threads x 2 slots
        {
            int o = t & 63, bq = t >> 6;
            #pragma unroll
            for (int j = 0; j < 2; ++j) {
                int b = bq + 16 * j;
                float vl = blds[b * ON_ + o];
                float m = vl;
                #pragma unroll
                for (int mm = 1; mm <= 32; mm <<= 1) m = fmaxf(m, __shfl_xor(m, mm, 64));
                float e = __expf(vl - m);
                float ss = e;
                #pragma unroll
                for (int mm = 1; mm <= 32; mm <<= 1) ss += __shfl_xor(ss, mm, 64);
                clds[b * ON_ + o] = e / ss;
            }
        }
        __syncthreads();

        // phase B: re-load fragment (L2-hit), re-issue MFMA, acc += c * xhat
        #pragma unroll
        for (int oi = 0; oi < 4; ++oi) {
            int o = wv * 4 + oi;
            union { uint4 u; short8 s; } bb;
            bb.u = wbf[((size_t)o * IN_ + i) * 64 + lane];
            f32x16 z = {};
            f32x16 C = __builtin_amdgcn_mfma_f32_32x32x16_bf16(af.s, bb.s, z, 0, 0, 0);
            #pragma unroll
            for (int r = 0; r < 16; ++r) {
                int b = (r & 3) + 8 * (r >> 2) + 4 * half;
                acc[oi][r] += clds[b * ON_ + o] * C[r];
            }
        }
    }

    float* dst = part + (size_t)ic * 65536;
    #pragma unroll
    for (int oi = 0; oi < 4; ++oi) {
        int o = wv * 4 + oi;
        #pragma unroll
        for (int r = 0; r < 16; ++r) {
            int b = (r & 3) + 8 * (r >> 2) + 4 * half;
            dst[(size_t)b * 2048 + o * 32 + d] = acc[oi][r];
        }
    }
}

// ---- reduce partials + squash (+optional add prev v) -----------------------
// grid 256, block 256 = 4 waves x 2 rows; row = b*64+o
__global__ __launch_bounds__(256) void reduce_squash_k(
    const float* __restrict__ part, int nslices, float scale,
    const float* __restrict__ addprev, float* __restrict__ outv, int out_bod)
{
    int t = threadIdx.x, lane = t & 63, wv = t >> 6;
    int row = blockIdx.x * 8 + wv * 2 + (lane >> 5);
    int d = lane & 31;
    const float* p = part + (size_t)row * 32 + d;
    float s0 = 0, s1 = 0, s2 = 0, s3 = 0, s4 = 0, s5 = 0, s6 = 0, s7 = 0;
    for (int s = 0; s < nslices; s += 8) {
        s0 += p[(size_t)(s + 0) * 65536];
        s1 += p[(size_t)(s + 1) * 65536];
        s2 += p[(size_t)(s + 2) * 65536];
        s3 += p[(size_t)(s + 3) * 65536];
        s4 += p[(size_t)(s + 4) * 65536];
        s5 += p[(size_t)(s + 5) * 65536];
        s6 += p[(size_t)(s + 6) * 65536];
        s7 += p[(size_t)(s + 7) * 65536];
    }
    float sv = (((s0 + s1) + (s2 + s3)) + ((s4 + s5) + (s6 + s7))) * scale;
    float n2 = sv * sv;
    #pragma unroll
    for (int m = 1; m <= 16; m <<= 1) n2 += __shfl_xor(n2, m, 32);
    float norm = sqrtf(n2);
    float sc = n2 / ((1.0f + n2) * (norm + 1e-8f));
    float v = sc * sv;
    int b = row >> 6, o = row & 63;
    if (addprev) v += addprev[((size_t)o * B_ + b) * OD_ + d];
    if (out_bod) outv[(size_t)row * OD_ + d] = v;
    else         outv[((size_t)o * B_ + b) * OD_ + d] = v;
}

// ============================ LEGACY PATH (round-1, proven) =================

__global__ __launch_bounds__(256, 4) void pass0_k(
    const float* __restrict__ x, const float* __restrict__ w, float* __restrict__ S)
{
    __shared__ __align__(16) unsigned short lw[16 * 512];
    __shared__ __align__(16) unsigned short lx[512];

    const int t = threadIdx.x, lane = t & 63, wv = t >> 6;
    const int bx = blockIdx.x;
    const int ic = bx & 255, og = bx >> 8;
    const int o0 = og * 16;
    const int d = lane & 31, half = lane >> 5;

    f32x16 acc[4] = {};

    for (int i = ic * 8; i < ic * 8 + 8; ++i) {
        #pragma unroll
        for (int r = 0; r < 4; ++r) {
            int cidx = r * 256 + t;
            int ol = cidx >> 6, j8 = cidx & 63;
            const float* g = w + (size_t)(o0 + ol) * 1048576 + (size_t)i * 512 + j8 * 8;
            float4 a = *(const float4*)g;
            float4 b2 = *(const float4*)(g + 4);
            uint4 val = { pack2(a.x, a.y), pack2(a.z, a.w), pack2(b2.x, b2.y), pack2(b2.z, b2.w) };
            *reinterpret_cast<uint4*>(&lw[ol * 512 + j8 * 8]) = val;
        }
        if (t < 128) {
            int b = t >> 2, kq = t & 3;
            float4 a = *(const float4*)(x + ((size_t)b * IN_ + i) * ID_ + kq * 4);
            uint2 val = { pack2(a.x, a.y), pack2(a.z, a.w) };
            *reinterpret_cast<uint2*>(&lx[b * 16 + kq * 4]) = val;
        }
        __syncthreads();

        short8 afr = *reinterpret_cast<const short8*>(&lx[(lane & 31) * 16 + half * 8]);
        #pragma unroll
        for (int oi = 0; oi < 4; ++oi) {
            int ol = wv * 4 + oi;
            short8 bfr = *reinterpret_cast<const short8*>(&lw[ol * 512 + d * 16 + half * 8]);
            acc[oi] = __builtin_amdgcn_mfma_f32_32x32x16_bf16(afr, bfr, acc[oi], 0, 0, 0);
        }
        __syncthreads();
    }

    #pragma unroll
    for (int oi = 0; oi < 4; ++oi) {
        int o = o0 + wv * 4 + oi;
        #pragma unroll
        for (int r = 0; r < 16; ++r) {
            int b = (r & 3) + 8 * (r >> 2) + 4 * half;
            atomicAdd(&S[((size_t)b * ON_ + o) * OD_ + d], acc[oi][r]);
        }
    }
}

__global__ __launch_bounds__(512, 2) void pass_route_k(
    const float* __restrict__ x, const float* __restrict__ w,
    const float* __restrict__ vin, float* __restrict__ S)
{
    __shared__ __align__(16) unsigned short lw[64 * 512];
    __shared__ __align__(16) unsigned short lx[512];
    __shared__ float blds[B_ * ON_];
    __shared__ float clds[B_ * ON_];

    const int t = threadIdx.x, lane = t & 63, wv = t >> 6;
    const int ic = blockIdx.x;
    const int d = lane & 31, half = lane >> 5;

    f32x16 acc[8] = {};

    for (int i = ic * 8; i < ic * 8 + 8; ++i) {
        #pragma unroll
        for (int r = 0; r < 8; ++r) {
            int cidx = r * 512 + t;
            int ol = cidx >> 6, j8 = cidx & 63;
            const float* g = w + (size_t)ol * 1048576 + (size_t)i * 512 + j8 * 8;
            float4 a = *(const float4*)g;
            float4 b2 = *(const float4*)(g + 4);
            uint4 val = { pack2(a.x, a.y), pack2(a.z, a.w), pack2(b2.x, b2.y), pack2(b2.z, b2.w) };
            *reinterpret_cast<uint4*>(&lw[ol * 512 + j8 * 8]) = val;
        }
        if (t < 128) {
            int b = t >> 2, kq = t & 3;
            float4 a = *(const float4*)(x + ((size_t)b * IN_ + i) * ID_ + kq * 4);
            uint2 val = { pack2(a.x, a.y), pack2(a.z, a.w) };
            *reinterpret_cast<uint2*>(&lx[b * 16 + kq * 4]) = val;
        }
        __syncthreads();

        short8 afr = *reinterpret_cast<const short8*>(&lx[(lane & 31) * 16 + half * 8]);
        short8 bfr[8];

        #pragma unroll
        for (int oi = 0; oi < 8; ++oi) {
            int o = wv * 8 + oi;
            bfr[oi] = *reinterpret_cast<const short8*>(&lw[o * 512 + d * 16 + half * 8]);
            f32x16 z = {};
            f32x16 C = __builtin_amdgcn_mfma_f32_32x32x16_bf16(afr, bfr[oi], z, 0, 0, 0);
            float bvp[16];
            #pragma unroll
            for (int r = 0; r < 16; ++r) {
                int b = (r & 3) + 8 * (r >> 2) + 4 * half;
                float vv = vin[((size_t)o * B_ + b) * OD_ + d];
                bvp[r] = C[r] * vv;
            }
            #pragma unroll
            for (int m = 1; m <= 16; m <<= 1) {
                #pragma unroll
                for (int r = 0; r < 16; ++r)
                    bvp[r] += __shfl_xor(bvp[r], m, 32);
            }
            if ((lane & 31) == 0) {
                #pragma unroll
                for (int r = 0; r < 16; ++r) {
                    int b = (r & 3) + 8 * (r >> 2) + 4 * half;
                    blds[b * ON_ + o] = bvp[r];
                }
            }
        }
        __syncthreads();

        {
            int o = t & 63, bq = t >> 6;
            #pragma unroll
            for (int j = 0; j < 4; ++j) {
                int b = bq + 8 * j;
                float v = blds[b * ON_ + o];
                float m = v;
                #pragma unroll
                for (int mm = 1; mm <= 32; mm <<= 1) m = fmaxf(m, __shfl_xor(m, mm, 64));
                float e = __expf(v - m);
                float ssum = e;
                #pragma unroll
                for (int mm = 1; mm <= 32; mm <<= 1) ssum += __shfl_xor(ssum, mm, 64);
                clds[b * ON_ + o] = e / ssum;
            }
        }
        __syncthreads();

        #pragma unroll
        for (int oi = 0; oi < 8; ++oi) {
            int o = wv * 8 + oi;
            f32x16 z = {};
            f32x16 C = __builtin_amdgcn_mfma_f32_32x32x16_bf16(afr, bfr[oi], z, 0, 0, 0);
            #pragma unroll
            for (int r = 0; r < 16; ++r) {
                int b = (r & 3) + 8 * (r >> 2) + 4 * half;
                acc[oi][r] += clds[b * ON_ + o] * C[r];
            }
        }
        __syncthreads();
    }

    #pragma unroll
    for (int oi = 0; oi < 8; ++oi) {
        int o = wv * 8 + oi;
        #pragma unroll
        for (int r = 0; r < 16; ++r) {
            int b = (r & 3) + 8 * (r >> 2) + 4 * half;
            atomicAdd(&S[((size_t)b * ON_ + o) * OD_ + d], acc[oi][r]);
        }
    }
}

__global__ __launch_bounds__(256) void squash_k(
    const float* __restrict__ S, const float* __restrict__ addprev,
    float* __restrict__ out, float scale, int out_bod)
{
    int t = threadIdx.x;
    int row = blockIdx.x * 8 + (t >> 5);
    int d = t & 31;
    int b = row >> 6, o = row & 63;
    float s = S[(size_t)row * OD_ + d] * scale;
    float n2 = s * s;
    #pragma unroll
    for (int mm = 1; mm <= 16; mm <<= 1) n2 += __shfl_xor(n2, mm, 32);
    float norm = sqrtf(n2);
    float sc = n2 / ((1.0f + n2) * (norm + 1e-8f));
    float v = sc * s;
    if (addprev) v += addprev[((size_t)o * B_ + b) * OD_ + d];
    if (out_bod)
        out[((size_t)b * ON_ + o) * OD_ + d] = v;
    else
        out[((size_t)o * B_ + b) * OD_ + d] = v;
}

// ============================ LAUNCHER ======================================

extern "C" void kernel_launch(void* const* d_in, const int* in_sizes, int n_in,
                              void* d_out, int out_size, void* d_ws, size_t ws_size,
                              hipStream_t stream) {
    (void)in_sizes; (void)n_in; (void)out_size;
    const float* x = (const float*)d_in[0];
    const float* w = (const float*)d_in[1];
    float* out = (float*)d_out;

    const size_t WBF_B  = 134217728;   // 64*2048*1024
    const size_t XBF_B  = 2097152;     // 2048*1024
    const size_t PART_B = 67108864;    // 256*65536*4
    const size_t V_B    = 262144;
    const size_t NEED   = WBF_B + XBF_B + PART_B + 2 * V_B;

    if (ws_size >= NEED) {
        uint8_t* wsb = (uint8_t*)d_ws;
        uint4* wbf  = (uint4*)wsb;
        uint4* xbf  = (uint4*)(wsb + WBF_B);
        float* part = (float*)(wsb + WBF_B + XBF_B);
        float* v0   = (float*)(wsb + WBF_B + XBF_B + PART_B);
        float* vsum = (float*)(wsb + WBF_B + XBF_B + PART_B + V_B);

        xconv_k<<<512, 256, 0, stream>>>(x, xbf);
        pass0_k2<<<256, 1024, 0, stream>>>(w, xbf, wbf, part);
        reduce_squash_k<<<256, 256, 0, stream>>>(part, 64, 1.0f / 64.0f, nullptr, v0, 0);
        route_k2<<<256, 1024, 0, stream>>>(wbf, xbf, v0, part);
        reduce_squash_k<<<256, 256, 0, stream>>>(part, 256, 1.0f, v0, vsum, 0);
        route_k2<<<256, 1024, 0, stream>>>(wbf, xbf, vsum, part);
        reduce_squash_k<<<256, 256, 0, stream>>>(part, 256, 1.0f, nullptr, out, 1);
    } else {
        // legacy (round-1) path — needs only 768 KB of ws
        float* S    = (float*)d_ws;
        float* v0   = S + 65536;
        float* vsum = v0 + 65536;
        const size_t Sbytes = (size_t)65536 * sizeof(float);

        hipMemsetAsync(S, 0, Sbytes, stream);
        pass0_k<<<1024, 256, 0, stream>>>(x, w, S);
        squash_k<<<256, 256, 0, stream>>>(S, nullptr, v0, 1.0f / 64.0f, 0);

        hipMemsetAsync(S, 0, Sbytes, stream);
        pass_route_k<<<256, 512, 0, stream>>>(x, w, v0, S);
        squash_k<<<256, 256, 0, stream>>>(S, v0, vsum, 1.0f, 0);

        hipMemsetAsync(S, 0, Sbytes, stream);
        pass_route_k<<<256, 512, 0, stream>>>(x, w, vsum, S);
        squash_k<<<256, 256, 0, stream>>>(S, nullptr, out, 1.0f, 1);
    }
}

// Round 4
// 462.339 us; speedup vs baseline: 1.4787x; 1.4787x over previous
//
#include <hip/hip_runtime.h>
#include <cstdint>

typedef __attribute__((ext_vector_type(8))) short short8;
typedef __attribute__((ext_vector_type(16))) float f32x16;

#define B_   32
#define IN_  2048
#define ID_  16
#define ON_  64
#define OD_  32
// weight strides (floats): o: 1048576, i: 512, d: 16, k: 1

__device__ __forceinline__ unsigned short f2bf(float f) {
    union { float f; uint32_t u; } c; c.f = f;
    uint32_t u = c.u;
    uint32_t r = (u + 0x7FFFu + ((u >> 16) & 1u)) >> 16;
    return (unsigned short)r;
}
__device__ __forceinline__ unsigned int pack2(float a, float b) {
    return (unsigned int)f2bf(a) | ((unsigned int)f2bf(b) << 16);
}

// ============================ FAST PATH =====================================
// ws layout (bytes):
//   wbf  : bf16 weight, MFMA B-frag order, uint4[(o*2048+i)*64+lane]  134,217,728
//   xbf  : bf16 x, MFMA A-frag order, uint4[i*64+lane]                  2,097,152
//   part : fp32 partials [64][b*2048+o*32+d]                           16,777,216
//   c_g  : fp32 coupling coeffs [i][o][b]                              16,777,216
//   v0, vsum : fp32 [o][b][d]                                             262,144 each

// ---- pack x -> A-fragment layout: lane holds x[b=lane&31, i, k=half*8+j] ----
__global__ __launch_bounds__(256) void xconv_k(
    const float* __restrict__ x, uint4* __restrict__ xbf)
{
    int t = threadIdx.x, lane = t & 63, wv = t >> 6;
    int i = blockIdx.x * 4 + wv;
    int b = lane & 31, half = lane >> 5;
    const float* g = x + ((size_t)b * IN_ + i) * ID_ + half * 8;
    float4 a = *(const float4*)g;
    float4 c = *(const float4*)(g + 4);
    uint4 p = { pack2(a.x, a.y), pack2(a.z, a.w), pack2(c.x, c.y), pack2(c.z, c.w) };
    xbf[(size_t)i * 64 + lane] = p;
}

// ---- pass0: read w fp32 direct->reg, emit wbf, MFMA-accumulate S0 partials --
// grid 256 = 64 ic (i-chunk 32) x 4 og (16 o). block 1024 = 16 waves x 1 o.
// acc = 16 regs only -> fits the 64-VGPR budget of 1024-thread blocks.
__global__ __launch_bounds__(1024) void pass0_k2(
    const float* __restrict__ w, const uint4* __restrict__ xbf,
    uint4* __restrict__ wbf, float* __restrict__ part)
{
    int t = threadIdx.x, lane = t & 63, wv = t >> 6;
    int og = blockIdx.x & 3, ic = blockIdx.x >> 2;
    int o = og * 16 + wv;
    int d = lane & 31, half = lane >> 5;

    f32x16 acc = {};
    #pragma unroll 4
    for (int ii = 0; ii < 32; ++ii) {
        int i = ic * 32 + ii;
        union { uint4 u; short8 s; } af;
        af.u = xbf[(size_t)i * 64 + lane];
        const float* g = w + ((size_t)o * IN_ + i) * 512 + d * 16 + half * 8;
        float4 a = *(const float4*)g;
        float4 c = *(const float4*)(g + 4);
        union { uint4 u; short8 s; } bf;
        bf.u = (uint4){ pack2(a.x, a.y), pack2(a.z, a.w), pack2(c.x, c.y), pack2(c.z, c.w) };
        wbf[((size_t)o * IN_ + i) * 64 + lane] = bf.u;
        acc = __builtin_amdgcn_mfma_f32_32x32x16_bf16(af.s, bf.s, acc, 0, 0, 0);
    }
    float* dst = part + (size_t)ic * 65536;
    #pragma unroll
    for (int r = 0; r < 16; ++r) {
        int b = (r & 3) + 8 * (r >> 2) + 4 * half;
        dst[(size_t)b * 2048 + o * 32 + d] = acc[r];
    }
}

// ---- logits + softmax: NO accumulator -> no spill risk ---------------------
// grid 256 ic (i-chunk 8). block 1024 = 16 waves x 4 o.
// Writes c_g[i][o][b] (fp32).
__global__ __launch_bounds__(1024) void logits_k(
    const uint4* __restrict__ wbf, const uint4* __restrict__ xbf,
    const float* __restrict__ vin /*[o][b][d]*/, float* __restrict__ c_g)
{
    __shared__ float blds[B_ * ON_];   // [b][o]

    int t = threadIdx.x, lane = t & 63, wv = t >> 6;
    int ic = blockIdx.x;
    int d = lane & 31, half = lane >> 5;

    for (int ii = 0; ii < 8; ++ii) {
        int i = ic * 8 + ii;
        union { uint4 u; short8 s; } af;
        af.u = xbf[(size_t)i * 64 + lane];

        #pragma unroll
        for (int oi = 0; oi < 4; ++oi) {
            int o = wv * 4 + oi;
            union { uint4 u; short8 s; } bb;
            bb.u = wbf[((size_t)o * IN_ + i) * 64 + lane];
            f32x16 z = {};
            f32x16 C = __builtin_amdgcn_mfma_f32_32x32x16_bf16(af.s, bb.s, z, 0, 0, 0);
            const float* vp = vin + (size_t)o * (B_ * OD_) + d;
            #pragma unroll
            for (int r = 0; r < 16; ++r) {
                int b = (r & 3) + 8 * (r >> 2) + 4 * half;
                C[r] *= vp[b * 32];
            }
            #pragma unroll
            for (int m = 1; m <= 16; m <<= 1) {
                #pragma unroll
                for (int r = 0; r < 16; ++r) C[r] += __shfl_xor(C[r], m, 32);
            }
            if ((lane & 31) == 0) {
                #pragma unroll
                for (int r = 0; r < 16; ++r) {
                    int b = (r & 3) + 8 * (r >> 2) + 4 * half;
                    blds[b * ON_ + o] = C[r];
                }
            }
        }
        __syncthreads();

        // softmax over o for each b; write c straight to global
        {
            int o = t & 63, bq = t >> 6;   // bq in [0,16)
            #pragma unroll
            for (int j = 0; j < 2; ++j) {
                int b = bq + 16 * j;
                float vl = blds[b * ON_ + o];
                float m = vl;
                #pragma unroll
                for (int mm = 1; mm <= 32; mm <<= 1) m = fmaxf(m, __shfl_xor(m, mm, 64));
                float e = __expf(vl - m);
                float ss = e;
                #pragma unroll
                for (int mm = 1; mm <= 32; mm <<= 1) ss += __shfl_xor(ss, mm, 64);
                c_g[(size_t)i * 2048 + o * 32 + b] = e / ss;
            }
        }
        __syncthreads();   // blds reused next ii
    }
}

// ---- accum: S partials = sum_i c[b,o,i] * xhat[b,o,i,:] --------------------
// grid 1024 = 16 ic x 64 o. block 256 = 4 waves, wave owns 32 i's. acc = 16 regs.
// c folded into A-fragment: lane's row b = lane&31 -> single scalar scale.
__global__ __launch_bounds__(256, 4) void accum_k(
    const uint4* __restrict__ wbf, const uint4* __restrict__ xbf,
    const float* __restrict__ c_g, float* __restrict__ part)
{
    int t = threadIdx.x, lane = t & 63, wv = t >> 6;
    int o = blockIdx.x & 63, ic = blockIdx.x >> 6;
    int d = lane & 31, half = lane >> 5;
    int i0 = ic * 128 + wv * 32;

    f32x16 acc = {};
    #pragma unroll 4
    for (int ii = 0; ii < 32; ++ii) {
        int i = i0 + ii;
        union { uint4 u; short8 s; } af;
        af.u = xbf[(size_t)i * 64 + lane];
        union { uint4 u; short8 s; } bb;
        bb.u = wbf[((size_t)o * IN_ + i) * 64 + lane];
        float cl = c_g[(size_t)i * 2048 + o * 32 + (lane & 31)];
        union { uint4 u; short8 s; } afs;
        #pragma unroll
        for (int j = 0; j < 4; ++j) {
            uint32_t p = ((const uint32_t*)&af.u)[j];
            union { float f; uint32_t u; } lo, hi;
            lo.u = (p & 0xFFFFu) << 16;
            hi.u = p & 0xFFFF0000u;
            ((uint32_t*)&afs.u)[j] = pack2(lo.f * cl, hi.f * cl);
        }
        acc = __builtin_amdgcn_mfma_f32_32x32x16_bf16(afs.s, bb.s, acc, 0, 0, 0);
    }

    float* dst = part + (size_t)(ic * 4 + wv) * 65536;
    #pragma unroll
    for (int r = 0; r < 16; ++r) {
        int b = (r & 3) + 8 * (r >> 2) + 4 * half;
        dst[(size_t)b * 2048 + o * 32 + d] = acc[r];
    }
}

// ---- reduce partials + squash (+optional add prev v) -----------------------
// grid 256, block 256 = 4 waves x 2 rows; row = b*64+o
__global__ __launch_bounds__(256) void reduce_squash_k(
    const float* __restrict__ part, int nslices, float scale,
    const float* __restrict__ addprev, float* __restrict__ outv, int out_bod)
{
    int t = threadIdx.x, lane = t & 63, wv = t >> 6;
    int row = blockIdx.x * 8 + wv * 2 + (lane >> 5);
    int d = lane & 31;
    const float* p = part + (size_t)row * 32 + d;
    float s0 = 0, s1 = 0, s2 = 0, s3 = 0, s4 = 0, s5 = 0, s6 = 0, s7 = 0;
    for (int s = 0; s < nslices; s += 8) {
        s0 += p[(size_t)(s + 0) * 65536];
        s1 += p[(size_t)(s + 1) * 65536];
        s2 += p[(size_t)(s + 2) * 65536];
        s3 += p[(size_t)(s + 3) * 65536];
        s4 += p[(size_t)(s + 4) * 65536];
        s5 += p[(size_t)(s + 5) * 65536];
        s6 += p[(size_t)(s + 6) * 65536];
        s7 += p[(size_t)(s + 7) * 65536];
    }
    float sv = (((s0 + s1) + (s2 + s3)) + ((s4 + s5) + (s6 + s7))) * scale;
    float n2 = sv * sv;
    #pragma unroll
    for (int m = 1; m <= 16; m <<= 1) n2 += __shfl_xor(n2, m, 32);
    float norm = sqrtf(n2);
    float sc = n2 / ((1.0f + n2) * (norm + 1e-8f));
    float v = sc * sv;
    int b = row >> 6, o = row & 63;
    if (addprev) v += addprev[((size_t)o * B_ + b) * OD_ + d];
    if (out_bod) outv[(size_t)row * OD_ + d] = v;
    else         outv[((size_t)o * B_ + b) * OD_ + d] = v;
}

// ============================ LEGACY PATH (round-1, proven) =================

__global__ __launch_bounds__(256, 4) void pass0_k(
    const float* __restrict__ x, const float* __restrict__ w, float* __restrict__ S)
{
    __shared__ __align__(16) unsigned short lw[16 * 512];
    __shared__ __align__(16) unsigned short lx[512];

    const int t = threadIdx.x, lane = t & 63, wv = t >> 6;
    const int bx = blockIdx.x;
    const int ic = bx & 255, og = bx >> 8;
    const int o0 = og * 16;
    const int d = lane & 31, half = lane >> 5;

    f32x16 acc[4] = {};

    for (int i = ic * 8; i < ic * 8 + 8; ++i) {
        #pragma unroll
        for (int r = 0; r < 4; ++r) {
            int cidx = r * 256 + t;
            int ol = cidx >> 6, j8 = cidx & 63;
            const float* g = w + (size_t)(o0 + ol) * 1048576 + (size_t)i * 512 + j8 * 8;
            float4 a = *(const float4*)g;
            float4 b2 = *(const float4*)(g + 4);
            uint4 val = { pack2(a.x, a.y), pack2(a.z, a.w), pack2(b2.x, b2.y), pack2(b2.z, b2.w) };
            *reinterpret_cast<uint4*>(&lw[ol * 512 + j8 * 8]) = val;
        }
        if (t < 128) {
            int b = t >> 2, kq = t & 3;
            float4 a = *(const float4*)(x + ((size_t)b * IN_ + i) * ID_ + kq * 4);
            uint2 val = { pack2(a.x, a.y), pack2(a.z, a.w) };
            *reinterpret_cast<uint2*>(&lx[b * 16 + kq * 4]) = val;
        }
        __syncthreads();

        short8 afr = *reinterpret_cast<const short8*>(&lx[(lane & 31) * 16 + half * 8]);
        #pragma unroll
        for (int oi = 0; oi < 4; ++oi) {
            int ol = wv * 4 + oi;
            short8 bfr = *reinterpret_cast<const short8*>(&lw[ol * 512 + d * 16 + half * 8]);
            acc[oi] = __builtin_amdgcn_mfma_f32_32x32x16_bf16(afr, bfr, acc[oi], 0, 0, 0);
        }
        __syncthreads();
    }

    #pragma unroll
    for (int oi = 0; oi < 4; ++oi) {
        int o = o0 + wv * 4 + oi;
        #pragma unroll
        for (int r = 0; r < 16; ++r) {
            int b = (r & 3) + 8 * (r >> 2) + 4 * half;
            atomicAdd(&S[((size_t)b * ON_ + o) * OD_ + d], acc[oi][r]);
        }
    }
}

__global__ __launch_bounds__(512, 2) void pass_route_k(
    const float* __restrict__ x, const float* __restrict__ w,
    const float* __restrict__ vin, float* __restrict__ S)
{
    __shared__ __align__(16) unsigned short lw[64 * 512];
    __shared__ __align__(16) unsigned short lx[512];
    __shared__ float blds[B_ * ON_];
    __shared__ float clds[B_ * ON_];

    const int t = threadIdx.x, lane = t & 63, wv = t >> 6;
    const int ic = blockIdx.x;
    const int d = lane & 31, half = lane >> 5;

    f32x16 acc[8] = {};

    for (int i = ic * 8; i < ic * 8 + 8; ++i) {
        #pragma unroll
        for (int r = 0; r < 8; ++r) {
            int cidx = r * 512 + t;
            int ol = cidx >> 6, j8 = cidx & 63;
            const float* g = w + (size_t)ol * 1048576 + (size_t)i * 512 + j8 * 8;
            float4 a = *(const float4*)g;
            float4 b2 = *(const float4*)(g + 4);
            uint4 val = { pack2(a.x, a.y), pack2(a.z, a.w), pack2(b2.x, b2.y), pack2(b2.z, b2.w) };
            *reinterpret_cast<uint4*>(&lw[ol * 512 + j8 * 8]) = val;
        }
        if (t < 128) {
            int b = t >> 2, kq = t & 3;
            float4 a = *(const float4*)(x + ((size_t)b * IN_ + i) * ID_ + kq * 4);
            uint2 val = { pack2(a.x, a.y), pack2(a.z, a.w) };
            *reinterpret_cast<uint2*>(&lx[b * 16 + kq * 4]) = val;
        }
        __syncthreads();

        short8 afr = *reinterpret_cast<const short8*>(&lx[(lane & 31) * 16 + half * 8]);
        short8 bfr[8];

        #pragma unroll
        for (int oi = 0; oi < 8; ++oi) {
            int o = wv * 8 + oi;
            bfr[oi] = *reinterpret_cast<const short8*>(&lw[o * 512 + d * 16 + half * 8]);
            f32x16 z = {};
            f32x16 C = __builtin_amdgcn_mfma_f32_32x32x16_bf16(afr, bfr[oi], z, 0, 0, 0);
            float bvp[16];
            #pragma unroll
            for (int r = 0; r < 16; ++r) {
                int b = (r & 3) + 8 * (r >> 2) + 4 * half;
                float vv = vin[((size_t)o * B_ + b) * OD_ + d];
                bvp[r] = C[r] * vv;
            }
            #pragma unroll
            for (int m = 1; m <= 16; m <<= 1) {
                #pragma unroll
                for (int r = 0; r < 16; ++r)
                    bvp[r] += __shfl_xor(bvp[r], m, 32);
            }
            if ((lane & 31) == 0) {
                #pragma unroll
                for (int r = 0; r < 16; ++r) {
                    int b = (r & 3) + 8 * (r >> 2) + 4 * half;
                    blds[b * ON_ + o] = bvp[r];
                }
            }
        }
        __syncthreads();

        {
            int o = t & 63, bq = t >> 6;
            #pragma unroll
            for (int j = 0; j < 4; ++j) {
                int b = bq + 8 * j;
                float v = blds[b * ON_ + o];
                float m = v;
                #pragma unroll
                for (int mm = 1; mm <= 32; mm <<= 1) m = fmaxf(m, __shfl_xor(m, mm, 64));
                float e = __expf(v - m);
                float ssum = e;
                #pragma unroll
                for (int mm = 1; mm <= 32; mm <<= 1) ssum += __shfl_xor(ssum, mm, 64);
                clds[b * ON_ + o] = e / ssum;
            }
        }
        __syncthreads();

        #pragma unroll
        for (int oi = 0; oi < 8; ++oi) {
            int o = wv * 8 + oi;
            f32x16 z = {};
            f32x16 C = __builtin_amdgcn_mfma_f32_32x32x16_bf16(afr, bfr[oi], z, 0, 0, 0);
            #pragma unroll
            for (int r = 0; r < 16; ++r) {
                int b = (r & 3) + 8 * (r >> 2) + 4 * half;
                acc[oi][r] += clds[b * ON_ + o] * C[r];
            }
        }
        __syncthreads();
    }

    #pragma unroll
    for (int oi = 0; oi < 8; ++oi) {
        int o = wv * 8 + oi;
        #pragma unroll
        for (int r = 0; r < 16; ++r) {
            int b = (r & 3) + 8 * (r >> 2) + 4 * half;
            atomicAdd(&S[((size_t)b * ON_ + o) * OD_ + d], acc[oi][r]);
        }
    }
}

__global__ __launch_bounds__(256) void squash_k(
    const float* __restrict__ S, const float* __restrict__ addprev,
    float* __restrict__ out, float scale, int out_bod)
{
    int t = threadIdx.x;
    int row = blockIdx.x * 8 + (t >> 5);
    int d = t & 31;
    int b = row >> 6, o = row & 63;
    float s = S[(size_t)row * OD_ + d] * scale;
    float n2 = s * s;
    #pragma unroll
    for (int mm = 1; mm <= 16; mm <<= 1) n2 += __shfl_xor(n2, mm, 32);
    float norm = sqrtf(n2);
    float sc = n2 / ((1.0f + n2) * (norm + 1e-8f));
    float v = sc * s;
    if (addprev) v += addprev[((size_t)o * B_ + b) * OD_ + d];
    if (out_bod)
        out[((size_t)b * ON_ + o) * OD_ + d] = v;
    else
        out[((size_t)o * B_ + b) * OD_ + d] = v;
}

// ============================ LAUNCHER ======================================

extern "C" void kernel_launch(void* const* d_in, const int* in_sizes, int n_in,
                              void* d_out, int out_size, void* d_ws, size_t ws_size,
                              hipStream_t stream) {
    (void)in_sizes; (void)n_in; (void)out_size;
    const float* x = (const float*)d_in[0];
    const float* w = (const float*)d_in[1];
    float* out = (float*)d_out;

    const size_t WBF_B  = 134217728;   // 64*2048*1024
    const size_t XBF_B  = 2097152;     // 2048*1024
    const size_t PART_B = 16777216;    // 64*65536*4
    const size_t C_B    = 16777216;    // 2048*2048*4
    const size_t V_B    = 262144;
    const size_t NEED   = WBF_B + XBF_B + PART_B + C_B + 2 * V_B;

    if (ws_size >= NEED) {
        uint8_t* wsb = (uint8_t*)d_ws;
        uint4* wbf  = (uint4*)wsb;
        uint4* xbf  = (uint4*)(wsb + WBF_B);
        float* part = (float*)(wsb + WBF_B + XBF_B);
        float* c_g  = (float*)(wsb + WBF_B + XBF_B + PART_B);
        float* v0   = (float*)(wsb + WBF_B + XBF_B + PART_B + C_B);
        float* vsum = (float*)(wsb + WBF_B + XBF_B + PART_B + C_B + V_B);

        xconv_k<<<512, 256, 0, stream>>>(x, xbf);
        pass0_k2<<<256, 1024, 0, stream>>>(w, xbf, wbf, part);
        reduce_squash_k<<<256, 256, 0, stream>>>(part, 64, 1.0f / 64.0f, nullptr, v0, 0);

        logits_k<<<256, 1024, 0, stream>>>(wbf, xbf, v0, c_g);
        accum_k<<<1024, 256, 0, stream>>>(wbf, xbf, c_g, part);
        reduce_squash_k<<<256, 256, 0, stream>>>(part, 64, 1.0f, v0, vsum, 0);

        logits_k<<<256, 1024, 0, stream>>>(wbf, xbf, vsum, c_g);
        accum_k<<<1024, 256, 0, stream>>>(wbf, xbf, c_g, part);
        reduce_squash_k<<<256, 256, 0, stream>>>(part, 64, 1.0f, nullptr, out, 1);
    } else {
        // legacy (round-1) path — needs only 768 KB of ws
        float* S    = (float*)d_ws;
        float* v0   = S + 65536;
        float* vsum = v0 + 65536;
        const size_t Sbytes = (size_t)65536 * sizeof(float);

        hipMemsetAsync(S, 0, Sbytes, stream);
        pass0_k<<<1024, 256, 0, stream>>>(x, w, S);
        squash_k<<<256, 256, 0, stream>>>(S, nullptr, v0, 1.0f / 64.0f, 0);

        hipMemsetAsync(S, 0, Sbytes, stream);
        pass_route_k<<<256, 512, 0, stream>>>(x, w, v0, S);
        squash_k<<<256, 256, 0, stream>>>(S, v0, vsum, 1.0f, 0);

        hipMemsetAsync(S, 0, Sbytes, stream);
        pass_route_k<<<256, 512, 0, stream>>>(x, w, vsum, S);
        squash_k<<<256, 256, 0, stream>>>(S, nullptr, out, 1.0f, 1);
    }
}

// Round 5
// 428.328 us; speedup vs baseline: 1.5961x; 1.0794x over previous
//
#include <hip/hip_runtime.h>
#include <cstdint>

typedef __attribute__((ext_vector_type(8))) short short8;
typedef __attribute__((ext_vector_type(16))) float f32x16;

#define B_   32
#define IN_  2048
#define ID_  16
#define ON_  64
#define OD_  32
// weight strides (floats): o: 1048576, i: 512, d: 16, k: 1

__device__ __forceinline__ unsigned short f2bf(float f) {
    union { float f; uint32_t u; } c; c.f = f;
    uint32_t u = c.u;
    uint32_t r = (u + 0x7FFFu + ((u >> 16) & 1u)) >> 16;
    return (unsigned short)r;
}
__device__ __forceinline__ unsigned int pack2(float a, float b) {
    return (unsigned int)f2bf(a) | ((unsigned int)f2bf(b) << 16);
}

// ============================ FAST PATH =====================================
// ws layout (bytes):
//   wbf  : bf16 weight, MFMA B-frag order, uint4[(o*2048+i)*64+lane]  134,217,728
//   xbf  : bf16 x, MFMA A-frag order, uint4[i*64+lane]                  2,097,152
//   part : fp32 partials [64][b*2048+o*32+d]                           16,777,216
//   c_g  : fp32 coupling coeffs [i][o][b]                              16,777,216
//   L    : fp32 raw logits [i][b][o]                                   16,777,216
//   v0, vsum : fp32 [o][b][d]                                             262,144 each

// ---- pack x -> A-fragment layout: lane holds x[b=lane&31, i, k=half*8+j] ----
__global__ __launch_bounds__(256) void xconv_k(
    const float* __restrict__ x, uint4* __restrict__ xbf)
{
    int t = threadIdx.x, lane = t & 63, wv = t >> 6;
    int i = blockIdx.x * 4 + wv;
    int b = lane & 31, half = lane >> 5;
    const float* g = x + ((size_t)b * IN_ + i) * ID_ + half * 8;
    float4 a = *(const float4*)g;
    float4 c = *(const float4*)(g + 4);
    uint4 p = { pack2(a.x, a.y), pack2(a.z, a.w), pack2(c.x, c.y), pack2(c.z, c.w) };
    xbf[(size_t)i * 64 + lane] = p;
}

// ---- pass0: read w fp32 direct->reg, emit wbf, MFMA-accumulate S0 partials --
// grid 256 = 64 ic (i-chunk 32) x 4 og (16 o). block 1024 = 16 waves x 1 o.
__global__ __launch_bounds__(1024) void pass0_k2(
    const float* __restrict__ w, const uint4* __restrict__ xbf,
    uint4* __restrict__ wbf, float* __restrict__ part)
{
    int t = threadIdx.x, lane = t & 63, wv = t >> 6;
    int og = blockIdx.x & 3, ic = blockIdx.x >> 2;
    int o = og * 16 + wv;
    int d = lane & 31, half = lane >> 5;

    f32x16 acc = {};
    #pragma unroll 4
    for (int ii = 0; ii < 32; ++ii) {
        int i = ic * 32 + ii;
        union { uint4 u; short8 s; } af;
        af.u = xbf[(size_t)i * 64 + lane];
        const float* g = w + ((size_t)o * IN_ + i) * 512 + d * 16 + half * 8;
        float4 a = *(const float4*)g;
        float4 c = *(const float4*)(g + 4);
        union { uint4 u; short8 s; } bf;
        bf.u = (uint4){ pack2(a.x, a.y), pack2(a.z, a.w), pack2(c.x, c.y), pack2(c.z, c.w) };
        wbf[((size_t)o * IN_ + i) * 64 + lane] = bf.u;
        acc = __builtin_amdgcn_mfma_f32_32x32x16_bf16(af.s, bf.s, acc, 0, 0, 0);
    }
    float* dst = part + (size_t)ic * 65536;
    #pragma unroll
    for (int r = 0; r < 16; ++r) {
        int b = (r & 3) + 8 * (r >> 2) + 4 * half;
        dst[(size_t)b * 2048 + o * 32 + d] = acc[r];
    }
}

// ---- raw logits: barrier-free, LDS-free, deep TLP --------------------------
// grid 4096 = (ic = bx>>6) x (o = bx&63). block 256 = 4 waves x 8 i.
// L[i][b][o] = dot_d(v[o,b,:], xhat[b,o,i,:])
__global__ __launch_bounds__(256) void logits_raw_k(
    const uint4* __restrict__ wbf, const uint4* __restrict__ xbf,
    const float* __restrict__ vin /*[o][b][d]*/, float* __restrict__ L)
{
    int t = threadIdx.x, lane = t & 63, wv = t >> 6;
    int o = blockIdx.x & 63, ic = blockIdx.x >> 6;
    int d = lane & 31, half = lane >> 5;

    // hoist v for this o: lane needs v[b(r,half)][d] for r=0..15
    float vr[16];
    #pragma unroll
    for (int r = 0; r < 16; ++r) {
        int b = (r & 3) + 8 * (r >> 2) + 4 * half;
        vr[r] = vin[(size_t)o * (B_ * OD_) + b * 32 + d];
    }

    for (int ii = 0; ii < 8; ++ii) {
        int i = ic * 32 + wv * 8 + ii;
        union { uint4 u; short8 s; } af, bb;
        af.u = xbf[(size_t)i * 64 + lane];
        bb.u = wbf[((size_t)o * IN_ + i) * 64 + lane];
        f32x16 z = {};
        f32x16 C = __builtin_amdgcn_mfma_f32_32x32x16_bf16(af.s, bb.s, z, 0, 0, 0);
        #pragma unroll
        for (int r = 0; r < 16; ++r) C[r] *= vr[r];
        #pragma unroll
        for (int m = 1; m <= 16; m <<= 1) {
            #pragma unroll
            for (int r = 0; r < 16; ++r) C[r] += __shfl_xor(C[r], m, 32);
        }
        if ((lane & 31) == 0) {
            #pragma unroll
            for (int r = 0; r < 16; ++r) {
                int b = (r & 3) + 8 * (r >> 2) + 4 * half;
                L[(size_t)i * 2048 + b * 64 + o] = C[r];
            }
        }
    }
}

// ---- softmax over o per (i,b): coalesced row read, shuffle softmax ---------
// grid 2048 (one i per block). block 512 = 8 waves; wave w, q: row b = w*4+q.
__global__ __launch_bounds__(512) void softmax_c_k(
    const float* __restrict__ L, float* __restrict__ c_g)
{
    int t = threadIdx.x, lane = t & 63, wv = t >> 6;
    int i = blockIdx.x;
    #pragma unroll
    for (int q = 0; q < 4; ++q) {
        int b = wv * 4 + q;
        float vl = L[(size_t)i * 2048 + b * 64 + lane];
        float m = vl;
        #pragma unroll
        for (int mm = 1; mm <= 32; mm <<= 1) m = fmaxf(m, __shfl_xor(m, mm, 64));
        float e = __expf(vl - m);
        float ss = e;
        #pragma unroll
        for (int mm = 1; mm <= 32; mm <<= 1) ss += __shfl_xor(ss, mm, 64);
        c_g[(size_t)i * 2048 + lane * 32 + b] = e / ss;
    }
}

// ---- accum: S partials = sum_i c[b,o,i] * xhat[b,o,i,:] --------------------
// grid 1024 = 16 ic x 64 o. block 256 = 4 waves, wave owns 32 i's. acc = 16 regs.
__global__ __launch_bounds__(256, 4) void accum_k(
    const uint4* __restrict__ wbf, const uint4* __restrict__ xbf,
    const float* __restrict__ c_g, float* __restrict__ part)
{
    int t = threadIdx.x, lane = t & 63, wv = t >> 6;
    int o = blockIdx.x & 63, ic = blockIdx.x >> 6;
    int d = lane & 31, half = lane >> 5;
    int i0 = ic * 128 + wv * 32;

    f32x16 acc = {};
    #pragma unroll 4
    for (int ii = 0; ii < 32; ++ii) {
        int i = i0 + ii;
        union { uint4 u; short8 s; } af;
        af.u = xbf[(size_t)i * 64 + lane];
        union { uint4 u; short8 s; } bb;
        bb.u = wbf[((size_t)o * IN_ + i) * 64 + lane];
        float cl = c_g[(size_t)i * 2048 + o * 32 + (lane & 31)];
        union { uint4 u; short8 s; } afs;
        #pragma unroll
        for (int j = 0; j < 4; ++j) {
            uint32_t p = ((const uint32_t*)&af.u)[j];
            union { float f; uint32_t u; } lo, hi;
            lo.u = (p & 0xFFFFu) << 16;
            hi.u = p & 0xFFFF0000u;
            ((uint32_t*)&afs.u)[j] = pack2(lo.f * cl, hi.f * cl);
        }
        acc = __builtin_amdgcn_mfma_f32_32x32x16_bf16(afs.s, bb.s, acc, 0, 0, 0);
    }

    float* dst = part + (size_t)(ic * 4 + wv) * 65536;
    #pragma unroll
    for (int r = 0; r < 16; ++r) {
        int b = (r & 3) + 8 * (r >> 2) + 4 * half;
        dst[(size_t)b * 2048 + o * 32 + d] = acc[r];
    }
}

// ---- reduce partials + squash (+optional add prev v) -----------------------
__global__ __launch_bounds__(256) void reduce_squash_k(
    const float* __restrict__ part, int nslices, float scale,
    const float* __restrict__ addprev, float* __restrict__ outv, int out_bod)
{
    int t = threadIdx.x, lane = t & 63, wv = t >> 6;
    int row = blockIdx.x * 8 + wv * 2 + (lane >> 5);
    int d = lane & 31;
    const float* p = part + (size_t)row * 32 + d;
    float s0 = 0, s1 = 0, s2 = 0, s3 = 0, s4 = 0, s5 = 0, s6 = 0, s7 = 0;
    for (int s = 0; s < nslices; s += 8) {
        s0 += p[(size_t)(s + 0) * 65536];
        s1 += p[(size_t)(s + 1) * 65536];
        s2 += p[(size_t)(s + 2) * 65536];
        s3 += p[(size_t)(s + 3) * 65536];
        s4 += p[(size_t)(s + 4) * 65536];
        s5 += p[(size_t)(s + 5) * 65536];
        s6 += p[(size_t)(s + 6) * 65536];
        s7 += p[(size_t)(s + 7) * 65536];
    }
    float sv = (((s0 + s1) + (s2 + s3)) + ((s4 + s5) + (s6 + s7))) * scale;
    float n2 = sv * sv;
    #pragma unroll
    for (int m = 1; m <= 16; m <<= 1) n2 += __shfl_xor(n2, m, 32);
    float norm = sqrtf(n2);
    float sc = n2 / ((1.0f + n2) * (norm + 1e-8f));
    float v = sc * sv;
    int b = row >> 6, o = row & 63;
    if (addprev) v += addprev[((size_t)o * B_ + b) * OD_ + d];
    if (out_bod) outv[(size_t)row * OD_ + d] = v;
    else         outv[((size_t)o * B_ + b) * OD_ + d] = v;
}

// ============================ LEGACY PATH (round-1, proven) =================

__global__ __launch_bounds__(256, 4) void pass0_k(
    const float* __restrict__ x, const float* __restrict__ w, float* __restrict__ S)
{
    __shared__ __align__(16) unsigned short lw[16 * 512];
    __shared__ __align__(16) unsigned short lx[512];

    const int t = threadIdx.x, lane = t & 63, wv = t >> 6;
    const int bx = blockIdx.x;
    const int ic = bx & 255, og = bx >> 8;
    const int o0 = og * 16;
    const int d = lane & 31, half = lane >> 5;

    f32x16 acc[4] = {};

    for (int i = ic * 8; i < ic * 8 + 8; ++i) {
        #pragma unroll
        for (int r = 0; r < 4; ++r) {
            int cidx = r * 256 + t;
            int ol = cidx >> 6, j8 = cidx & 63;
            const float* g = w + (size_t)(o0 + ol) * 1048576 + (size_t)i * 512 + j8 * 8;
            float4 a = *(const float4*)g;
            float4 b2 = *(const float4*)(g + 4);
            uint4 val = { pack2(a.x, a.y), pack2(a.z, a.w), pack2(b2.x, b2.y), pack2(b2.z, b2.w) };
            *reinterpret_cast<uint4*>(&lw[ol * 512 + j8 * 8]) = val;
        }
        if (t < 128) {
            int b = t >> 2, kq = t & 3;
            float4 a = *(const float4*)(x + ((size_t)b * IN_ + i) * ID_ + kq * 4);
            uint2 val = { pack2(a.x, a.y), pack2(a.z, a.w) };
            *reinterpret_cast<uint2*>(&lx[b * 16 + kq * 4]) = val;
        }
        __syncthreads();

        short8 afr = *reinterpret_cast<const short8*>(&lx[(lane & 31) * 16 + half * 8]);
        #pragma unroll
        for (int oi = 0; oi < 4; ++oi) {
            int ol = wv * 4 + oi;
            short8 bfr = *reinterpret_cast<const short8*>(&lw[ol * 512 + d * 16 + half * 8]);
            acc[oi] = __builtin_amdgcn_mfma_f32_32x32x16_bf16(afr, bfr, acc[oi], 0, 0, 0);
        }
        __syncthreads();
    }

    #pragma unroll
    for (int oi = 0; oi < 4; ++oi) {
        int o = o0 + wv * 4 + oi;
        #pragma unroll
        for (int r = 0; r < 16; ++r) {
            int b = (r & 3) + 8 * (r >> 2) + 4 * half;
            atomicAdd(&S[((size_t)b * ON_ + o) * OD_ + d], acc[oi][r]);
        }
    }
}

__global__ __launch_bounds__(512, 2) void pass_route_k(
    const float* __restrict__ x, const float* __restrict__ w,
    const float* __restrict__ vin, float* __restrict__ S)
{
    __shared__ __align__(16) unsigned short lw[64 * 512];
    __shared__ __align__(16) unsigned short lx[512];
    __shared__ float blds[B_ * ON_];
    __shared__ float clds[B_ * ON_];

    const int t = threadIdx.x, lane = t & 63, wv = t >> 6;
    const int ic = blockIdx.x;
    const int d = lane & 31, half = lane >> 5;

    f32x16 acc[8] = {};

    for (int i = ic * 8; i < ic * 8 + 8; ++i) {
        #pragma unroll
        for (int r = 0; r < 8; ++r) {
            int cidx = r * 512 + t;
            int ol = cidx >> 6, j8 = cidx & 63;
            const float* g = w + (size_t)ol * 1048576 + (size_t)i * 512 + j8 * 8;
            float4 a = *(const float4*)g;
            float4 b2 = *(const float4*)(g + 4);
            uint4 val = { pack2(a.x, a.y), pack2(a.z, a.w), pack2(b2.x, b2.y), pack2(b2.z, b2.w) };
            *reinterpret_cast<uint4*>(&lw[ol * 512 + j8 * 8]) = val;
        }
        if (t < 128) {
            int b = t >> 2, kq = t & 3;
            float4 a = *(const float4*)(x + ((size_t)b * IN_ + i) * ID_ + kq * 4);
            uint2 val = { pack2(a.x, a.y), pack2(a.z, a.w) };
            *reinterpret_cast<uint2*>(&lx[b * 16 + kq * 4]) = val;
        }
        __syncthreads();

        short8 afr = *reinterpret_cast<const short8*>(&lx[(lane & 31) * 16 + half * 8]);
        short8 bfr[8];

        #pragma unroll
        for (int oi = 0; oi < 8; ++oi) {
            int o = wv * 8 + oi;
            bfr[oi] = *reinterpret_cast<const short8*>(&lw[o * 512 + d * 16 + half * 8]);
            f32x16 z = {};
            f32x16 C = __builtin_amdgcn_mfma_f32_32x32x16_bf16(afr, bfr[oi], z, 0, 0, 0);
            float bvp[16];
            #pragma unroll
            for (int r = 0; r < 16; ++r) {
                int b = (r & 3) + 8 * (r >> 2) + 4 * half;
                float vv = vin[((size_t)o * B_ + b) * OD_ + d];
                bvp[r] = C[r] * vv;
            }
            #pragma unroll
            for (int m = 1; m <= 16; m <<= 1) {
                #pragma unroll
                for (int r = 0; r < 16; ++r)
                    bvp[r] += __shfl_xor(bvp[r], m, 32);
            }
            if ((lane & 31) == 0) {
                #pragma unroll
                for (int r = 0; r < 16; ++r) {
                    int b = (r & 3) + 8 * (r >> 2) + 4 * half;
                    blds[b * ON_ + o] = bvp[r];
                }
            }
        }
        __syncthreads();

        {
            int o = t & 63, bq = t >> 6;
            #pragma unroll
            for (int j = 0; j < 4; ++j) {
                int b = bq + 8 * j;
                float v = blds[b * ON_ + o];
                float m = v;
                #pragma unroll
                for (int mm = 1; mm <= 32; mm <<= 1) m = fmaxf(m, __shfl_xor(m, mm, 64));
                float e = __expf(v - m);
                float ssum = e;
                #pragma unroll
                for (int mm = 1; mm <= 32; mm <<= 1) ssum += __shfl_xor(ssum, mm, 64);
                clds[b * ON_ + o] = e / ssum;
            }
        }
        __syncthreads();

        #pragma unroll
        for (int oi = 0; oi < 8; ++oi) {
            int o = wv * 8 + oi;
            f32x16 z = {};
            f32x16 C = __builtin_amdgcn_mfma_f32_32x32x16_bf16(afr, bfr[oi], z, 0, 0, 0);
            #pragma unroll
            for (int r = 0; r < 16; ++r) {
                int b = (r & 3) + 8 * (r >> 2) + 4 * half;
                acc[oi][r] += clds[b * ON_ + o] * C[r];
            }
        }
        __syncthreads();
    }

    #pragma unroll
    for (int oi = 0; oi < 8; ++oi) {
        int o = wv * 8 + oi;
        #pragma unroll
        for (int r = 0; r < 16; ++r) {
            int b = (r & 3) + 8 * (r >> 2) + 4 * half;
            atomicAdd(&S[((size_t)b * ON_ + o) * OD_ + d], acc[oi][r]);
        }
    }
}

__global__ __launch_bounds__(256) void squash_k(
    const float* __restrict__ S, const float* __restrict__ addprev,
    float* __restrict__ out, float scale, int out_bod)
{
    int t = threadIdx.x;
    int row = blockIdx.x * 8 + (t >> 5);
    int d = t & 31;
    int b = row >> 6, o = row & 63;
    float s = S[(size_t)row * OD_ + d] * scale;
    float n2 = s * s;
    #pragma unroll
    for (int mm = 1; mm <= 16; mm <<= 1) n2 += __shfl_xor(n2, mm, 32);
    float norm = sqrtf(n2);
    float sc = n2 / ((1.0f + n2) * (norm + 1e-8f));
    float v = sc * s;
    if (addprev) v += addprev[((size_t)o * B_ + b) * OD_ + d];
    if (out_bod)
        out[((size_t)b * ON_ + o) * OD_ + d] = v;
    else
        out[((size_t)o * B_ + b) * OD_ + d] = v;
}

// ============================ LAUNCHER ======================================

extern "C" void kernel_launch(void* const* d_in, const int* in_sizes, int n_in,
                              void* d_out, int out_size, void* d_ws, size_t ws_size,
                              hipStream_t stream) {
    (void)in_sizes; (void)n_in; (void)out_size;
    const float* x = (const float*)d_in[0];
    const float* w = (const float*)d_in[1];
    float* out = (float*)d_out;

    const size_t WBF_B  = 134217728;   // 64*2048*1024
    const size_t XBF_B  = 2097152;     // 2048*1024
    const size_t PART_B = 16777216;    // 64*65536*4
    const size_t C_B    = 16777216;    // 2048*2048*4
    const size_t L_B    = 16777216;    // 2048*2048*4
    const size_t V_B    = 262144;
    const size_t NEED   = WBF_B + XBF_B + PART_B + C_B + L_B + 2 * V_B;

    if (ws_size >= NEED) {
        uint8_t* wsb = (uint8_t*)d_ws;
        uint4* wbf  = (uint4*)wsb;
        uint4* xbf  = (uint4*)(wsb + WBF_B);
        float* part = (float*)(wsb + WBF_B + XBF_B);
        float* c_g  = (float*)(wsb + WBF_B + XBF_B + PART_B);
        float* Lg   = (float*)(wsb + WBF_B + XBF_B + PART_B + C_B);
        float* v0   = (float*)(wsb + WBF_B + XBF_B + PART_B + C_B + L_B);
        float* vsum = (float*)(wsb + WBF_B + XBF_B + PART_B + C_B + L_B + V_B);

        xconv_k<<<512, 256, 0, stream>>>(x, xbf);
        pass0_k2<<<256, 1024, 0, stream>>>(w, xbf, wbf, part);
        reduce_squash_k<<<256, 256, 0, stream>>>(part, 64, 1.0f / 64.0f, nullptr, v0, 0);

        logits_raw_k<<<4096, 256, 0, stream>>>(wbf, xbf, v0, Lg);
        softmax_c_k<<<2048, 512, 0, stream>>>(Lg, c_g);
        accum_k<<<1024, 256, 0, stream>>>(wbf, xbf, c_g, part);
        reduce_squash_k<<<256, 256, 0, stream>>>(part, 64, 1.0f, v0, vsum, 0);

        logits_raw_k<<<4096, 256, 0, stream>>>(wbf, xbf, vsum, Lg);
        softmax_c_k<<<2048, 512, 0, stream>>>(Lg, c_g);
        accum_k<<<1024, 256, 0, stream>>>(wbf, xbf, c_g, part);
        reduce_squash_k<<<256, 256, 0, stream>>>(part, 64, 1.0f, nullptr, out, 1);
    } else {
        // legacy (round-1) path — needs only 768 KB of ws
        float* S    = (float*)d_ws;
        float* v0   = S + 65536;
        float* vsum = v0 + 65536;
        const size_t Sbytes = (size_t)65536 * sizeof(float);

        hipMemsetAsync(S, 0, Sbytes, stream);
        pass0_k<<<1024, 256, 0, stream>>>(x, w, S);
        squash_k<<<256, 256, 0, stream>>>(S, nullptr, v0, 1.0f / 64.0f, 0);

        hipMemsetAsync(S, 0, Sbytes, stream);
        pass_route_k<<<256, 512, 0, stream>>>(x, w, v0, S);
        squash_k<<<256, 256, 0, stream>>>(S, v0, vsum, 1.0f, 0);

        hipMemsetAsync(S, 0, Sbytes, stream);
        pass_route_k<<<256, 512, 0, stream>>>(x, w, vsum, S);
        squash_k<<<256, 256, 0, stream>>>(S, nullptr, out, 1.0f, 1);
    }
}

// Round 6
// 342.635 us; speedup vs baseline: 1.9953x; 1.2501x over previous
//
#include <hip/hip_runtime.h>
#include <cstdint>

typedef __attribute__((ext_vector_type(8))) short short8;
typedef __attribute__((ext_vector_type(16))) float f32x16;

#define B_   32
#define IN_  2048
#define ID_  16
#define ON_  64
#define OD_  32
// weight strides (floats): o: 1048576, i: 512, d: 16, k: 1

__device__ __forceinline__ unsigned short f2bf(float f) {
    union { float f; uint32_t u; } c; c.f = f;
    uint32_t u = c.u;
    uint32_t r = (u + 0x7FFFu + ((u >> 16) & 1u)) >> 16;
    return (unsigned short)r;
}
__device__ __forceinline__ unsigned int pack2(float a, float b) {
    return (unsigned int)f2bf(a) | ((unsigned int)f2bf(b) << 16);
}

// ============================ FAST PATH =====================================
// ws layout (bytes):
//   wbf  : bf16 weight, MFMA frag order, uint4[(o*2048+i)*64+lane]    134,217,728
//   xbf  : bf16 x, MFMA frag order, uint4[i*64+lane]                    2,097,152
//   part : fp32 partials [64][b*2048+o*32+d]                           16,777,216
//   c_g  : fp32 coupling coeffs [i][o][b]                              16,777,216
//   L    : fp32 raw logits [i][b][o]                                   16,777,216
//   v0, vsum : fp32 [o][b][d]                                             262,144 each
//
// Fragment symmetry note: per-lane data {elem j at (lane&31, k=(lane>>5)*8+j)}
// serves as BOTH the A-operand (m=lane&31) and B-operand (n=lane&31) of
// v_mfma_f32_32x32x16_bf16. So mfma(af,bb) gives xhat[b][d] and mfma(bb,af)
// gives xhat^T[d][b] with no re-layout.

// ---- pack x -> frag layout: lane holds x[b=lane&31, i, k=half*8+j] ---------
__global__ __launch_bounds__(256) void xconv_k(
    const float* __restrict__ x, uint4* __restrict__ xbf)
{
    int t = threadIdx.x, lane = t & 63, wv = t >> 6;
    int i = blockIdx.x * 4 + wv;
    int b = lane & 31, half = lane >> 5;
    const float* g = x + ((size_t)b * IN_ + i) * ID_ + half * 8;
    float4 a = *(const float4*)g;
    float4 c = *(const float4*)(g + 4);
    uint4 p = { pack2(a.x, a.y), pack2(a.z, a.w), pack2(c.x, c.y), pack2(c.z, c.w) };
    xbf[(size_t)i * 64 + lane] = p;
}

// ---- pass0: read w fp32 direct->reg, emit wbf, MFMA-accumulate S0 partials --
// grid 256 = 64 ic (i-chunk 32) x 4 og (16 o). block 1024 = 16 waves x 1 o.
__global__ __launch_bounds__(1024) void pass0_k2(
    const float* __restrict__ w, const uint4* __restrict__ xbf,
    uint4* __restrict__ wbf, float* __restrict__ part)
{
    int t = threadIdx.x, lane = t & 63, wv = t >> 6;
    int og = blockIdx.x & 3, ic = blockIdx.x >> 2;
    int o = og * 16 + wv;
    int d = lane & 31, half = lane >> 5;

    f32x16 acc = {};
    #pragma unroll 4
    for (int ii = 0; ii < 32; ++ii) {
        int i = ic * 32 + ii;
        union { uint4 u; short8 s; } af;
        af.u = xbf[(size_t)i * 64 + lane];
        const float* g = w + ((size_t)o * IN_ + i) * 512 + d * 16 + half * 8;
        float4 a = *(const float4*)g;
        float4 c = *(const float4*)(g + 4);
        union { uint4 u; short8 s; } bf;
        bf.u = (uint4){ pack2(a.x, a.y), pack2(a.z, a.w), pack2(c.x, c.y), pack2(c.z, c.w) };
        wbf[((size_t)o * IN_ + i) * 64 + lane] = bf.u;
        acc = __builtin_amdgcn_mfma_f32_32x32x16_bf16(af.s, bf.s, acc, 0, 0, 0);
    }
    float* dst = part + (size_t)ic * 65536;
    #pragma unroll
    for (int r = 0; r < 16; ++r) {
        int b = (r & 3) + 8 * (r >> 2) + 4 * half;
        dst[(size_t)b * 2048 + o * 32 + d] = acc[r];
    }
}

// ---- raw logits via swapped-operand MFMA: in-lane dot, ONE shuffle ---------
// grid 4096 = (ic = bx>>6) x (o = bx&63). block 256 = 4 waves x 8 i.
// C2 = mfma(wbf, xbf) = xhat^T : col=lane&31=b, row d=(r&3)+8*(r>>2)+4*half.
// L[i][b][o] = sum_d v[o,b,d]*xhat[b,o,i,d] = in-lane 16-FMA + half-exchange.
__global__ __launch_bounds__(256) void logits_raw_k(
    const uint4* __restrict__ wbf, const uint4* __restrict__ xbf,
    const float* __restrict__ vin /*[o][b][d]*/, float* __restrict__ L)
{
    int t = threadIdx.x, lane = t & 63, wv = t >> 6;
    int o = blockIdx.x & 63, ic = blockIdx.x >> 6;
    int b = lane & 31, half = lane >> 5;

    // hoist v for this o: lane needs v[o][b=lane&31][d(r,half)] for r=0..15
    float vr[16];
    #pragma unroll
    for (int r = 0; r < 16; ++r) {
        int d = (r & 3) + 8 * (r >> 2) + 4 * half;
        vr[r] = vin[(size_t)o * (B_ * OD_) + b * 32 + d];
    }

    for (int ii = 0; ii < 8; ++ii) {
        int i = ic * 32 + wv * 8 + ii;
        union { uint4 u; short8 s; } af, bb;
        af.u = xbf[(size_t)i * 64 + lane];
        bb.u = wbf[((size_t)o * IN_ + i) * 64 + lane];
        f32x16 z = {};
        f32x16 C2 = __builtin_amdgcn_mfma_f32_32x32x16_bf16(bb.s, af.s, z, 0, 0, 0);
        float p0 = C2[0] * vr[0], p1 = C2[1] * vr[1];
        float p2 = C2[2] * vr[2], p3 = C2[3] * vr[3];
        #pragma unroll
        for (int r = 4; r < 16; r += 4) {
            p0 += C2[r + 0] * vr[r + 0];
            p1 += C2[r + 1] * vr[r + 1];
            p2 += C2[r + 2] * vr[r + 2];
            p3 += C2[r + 3] * vr[r + 3];
        }
        float partial = (p0 + p1) + (p2 + p3);
        float total = partial + __shfl_xor(partial, 32);   // add other-half d's
        if (half == 0)
            L[(size_t)i * 2048 + b * 64 + o] = total;
    }
}

// ---- softmax over o per (i,b): coalesced row read, shuffle softmax ---------
// grid 2048 (one i per block). block 512 = 8 waves; wave w, q: row b = w*4+q.
__global__ __launch_bounds__(512) void softmax_c_k(
    const float* __restrict__ L, float* __restrict__ c_g)
{
    int t = threadIdx.x, lane = t & 63, wv = t >> 6;
    int i = blockIdx.x;
    #pragma unroll
    for (int q = 0; q < 4; ++q) {
        int b = wv * 4 + q;
        float vl = L[(size_t)i * 2048 + b * 64 + lane];
        float m = vl;
        #pragma unroll
        for (int mm = 1; mm <= 32; mm <<= 1) m = fmaxf(m, __shfl_xor(m, mm, 64));
        float e = __expf(vl - m);
        float ss = e;
        #pragma unroll
        for (int mm = 1; mm <= 32; mm <<= 1) ss += __shfl_xor(ss, mm, 64);
        c_g[(size_t)i * 2048 + lane * 32 + b] = e / ss;
    }
}

// ---- accum: S partials = sum_i c[b,o,i] * xhat[b,o,i,:] --------------------
// grid 1024 = 16 ic x 64 o. block 256 = 4 waves, wave owns 32 i's. acc = 16 regs.
__global__ __launch_bounds__(256, 4) void accum_k(
    const uint4* __restrict__ wbf, const uint4* __restrict__ xbf,
    const float* __restrict__ c_g, float* __restrict__ part)
{
    int t = threadIdx.x, lane = t & 63, wv = t >> 6;
    int o = blockIdx.x & 63, ic = blockIdx.x >> 6;
    int d = lane & 31, half = lane >> 5;
    int i0 = ic * 128 + wv * 32;

    f32x16 acc = {};
    #pragma unroll 4
    for (int ii = 0; ii < 32; ++ii) {
        int i = i0 + ii;
        union { uint4 u; short8 s; } af;
        af.u = xbf[(size_t)i * 64 + lane];
        union { uint4 u; short8 s; } bb;
        bb.u = wbf[((size_t)o * IN_ + i) * 64 + lane];
        float cl = c_g[(size_t)i * 2048 + o * 32 + (lane & 31)];
        union { uint4 u; short8 s; } afs;
        #pragma unroll
        for (int j = 0; j < 4; ++j) {
            uint32_t p = ((const uint32_t*)&af.u)[j];
            union { float f; uint32_t u; } lo, hi;
            lo.u = (p & 0xFFFFu) << 16;
            hi.u = p & 0xFFFF0000u;
            ((uint32_t*)&afs.u)[j] = pack2(lo.f * cl, hi.f * cl);
        }
        acc = __builtin_amdgcn_mfma_f32_32x32x16_bf16(afs.s, bb.s, acc, 0, 0, 0);
    }

    float* dst = part + (size_t)(ic * 4 + wv) * 65536;
    #pragma unroll
    for (int r = 0; r < 16; ++r) {
        int b = (r & 3) + 8 * (r >> 2) + 4 * half;
        dst[(size_t)b * 2048 + o * 32 + d] = acc[r];
    }
}

// ---- reduce partials + squash (+optional add prev v) -----------------------
__global__ __launch_bounds__(256) void reduce_squash_k(
    const float* __restrict__ part, int nslices, float scale,
    const float* __restrict__ addprev, float* __restrict__ outv, int out_bod)
{
    int t = threadIdx.x, lane = t & 63, wv = t >> 6;
    int row = blockIdx.x * 8 + wv * 2 + (lane >> 5);
    int d = lane & 31;
    const float* p = part + (size_t)row * 32 + d;
    float s0 = 0, s1 = 0, s2 = 0, s3 = 0, s4 = 0, s5 = 0, s6 = 0, s7 = 0;
    for (int s = 0; s < nslices; s += 8) {
        s0 += p[(size_t)(s + 0) * 65536];
        s1 += p[(size_t)(s + 1) * 65536];
        s2 += p[(size_t)(s + 2) * 65536];
        s3 += p[(size_t)(s + 3) * 65536];
        s4 += p[(size_t)(s + 4) * 65536];
        s5 += p[(size_t)(s + 5) * 65536];
        s6 += p[(size_t)(s + 6) * 65536];
        s7 += p[(size_t)(s + 7) * 65536];
    }
    float sv = (((s0 + s1) + (s2 + s3)) + ((s4 + s5) + (s6 + s7))) * scale;
    float n2 = sv * sv;
    #pragma unroll
    for (int m = 1; m <= 16; m <<= 1) n2 += __shfl_xor(n2, m, 32);
    float norm = sqrtf(n2);
    float sc = n2 / ((1.0f + n2) * (norm + 1e-8f));
    float v = sc * sv;
    int b = row >> 6, o = row & 63;
    if (addprev) v += addprev[((size_t)o * B_ + b) * OD_ + d];
    if (out_bod) outv[(size_t)row * OD_ + d] = v;
    else         outv[((size_t)o * B_ + b) * OD_ + d] = v;
}

// ============================ LEGACY PATH (round-1, proven) =================

__global__ __launch_bounds__(256, 4) void pass0_k(
    const float* __restrict__ x, const float* __restrict__ w, float* __restrict__ S)
{
    __shared__ __align__(16) unsigned short lw[16 * 512];
    __shared__ __align__(16) unsigned short lx[512];

    const int t = threadIdx.x, lane = t & 63, wv = t >> 6;
    const int bx = blockIdx.x;
    const int ic = bx & 255, og = bx >> 8;
    const int o0 = og * 16;
    const int d = lane & 31, half = lane >> 5;

    f32x16 acc[4] = {};

    for (int i = ic * 8; i < ic * 8 + 8; ++i) {
        #pragma unroll
        for (int r = 0; r < 4; ++r) {
            int cidx = r * 256 + t;
            int ol = cidx >> 6, j8 = cidx & 63;
            const float* g = w + (size_t)(o0 + ol) * 1048576 + (size_t)i * 512 + j8 * 8;
            float4 a = *(const float4*)g;
            float4 b2 = *(const float4*)(g + 4);
            uint4 val = { pack2(a.x, a.y), pack2(a.z, a.w), pack2(b2.x, b2.y), pack2(b2.z, b2.w) };
            *reinterpret_cast<uint4*>(&lw[ol * 512 + j8 * 8]) = val;
        }
        if (t < 128) {
            int b = t >> 2, kq = t & 3;
            float4 a = *(const float4*)(x + ((size_t)b * IN_ + i) * ID_ + kq * 4);
            uint2 val = { pack2(a.x, a.y), pack2(a.z, a.w) };
            *reinterpret_cast<uint2*>(&lx[b * 16 + kq * 4]) = val;
        }
        __syncthreads();

        short8 afr = *reinterpret_cast<const short8*>(&lx[(lane & 31) * 16 + half * 8]);
        #pragma unroll
        for (int oi = 0; oi < 4; ++oi) {
            int ol = wv * 4 + oi;
            short8 bfr = *reinterpret_cast<const short8*>(&lw[ol * 512 + d * 16 + half * 8]);
            acc[oi] = __builtin_amdgcn_mfma_f32_32x32x16_bf16(afr, bfr, acc[oi], 0, 0, 0);
        }
        __syncthreads();
    }

    #pragma unroll
    for (int oi = 0; oi < 4; ++oi) {
        int o = o0 + wv * 4 + oi;
        #pragma unroll
        for (int r = 0; r < 16; ++r) {
            int b = (r & 3) + 8 * (r >> 2) + 4 * half;
            atomicAdd(&S[((size_t)b * ON_ + o) * OD_ + d], acc[oi][r]);
        }
    }
}

__global__ __launch_bounds__(512, 2) void pass_route_k(
    const float* __restrict__ x, const float* __restrict__ w,
    const float* __restrict__ vin, float* __restrict__ S)
{
    __shared__ __align__(16) unsigned short lw[64 * 512];
    __shared__ __align__(16) unsigned short lx[512];
    __shared__ float blds[B_ * ON_];
    __shared__ float clds[B_ * ON_];

    const int t = threadIdx.x, lane = t & 63, wv = t >> 6;
    const int ic = blockIdx.x;
    const int d = lane & 31, half = lane >> 5;

    f32x16 acc[8] = {};

    for (int i = ic * 8; i < ic * 8 + 8; ++i) {
        #pragma unroll
        for (int r = 0; r < 8; ++r) {
            int cidx = r * 512 + t;
            int ol = cidx >> 6, j8 = cidx & 63;
            const float* g = w + (size_t)ol * 1048576 + (size_t)i * 512 + j8 * 8;
            float4 a = *(const float4*)g;
            float4 b2 = *(const float4*)(g + 4);
            uint4 val = { pack2(a.x, a.y), pack2(a.z, a.w), pack2(b2.x, b2.y), pack2(b2.z, b2.w) };
            *reinterpret_cast<uint4*>(&lw[ol * 512 + j8 * 8]) = val;
        }
        if (t < 128) {
            int b = t >> 2, kq = t & 3;
            float4 a = *(const float4*)(x + ((size_t)b * IN_ + i) * ID_ + kq * 4);
            uint2 val = { pack2(a.x, a.y), pack2(a.z, a.w) };
            *reinterpret_cast<uint2*>(&lx[b * 16 + kq * 4]) = val;
        }
        __syncthreads();

        short8 afr = *reinterpret_cast<const short8*>(&lx[(lane & 31) * 16 + half * 8]);
        short8 bfr[8];

        #pragma unroll
        for (int oi = 0; oi < 8; ++oi) {
            int o = wv * 8 + oi;
            bfr[oi] = *reinterpret_cast<const short8*>(&lw[o * 512 + d * 16 + half * 8]);
            f32x16 z = {};
            f32x16 C = __builtin_amdgcn_mfma_f32_32x32x16_bf16(afr, bfr[oi], z, 0, 0, 0);
            float bvp[16];
            #pragma unroll
            for (int r = 0; r < 16; ++r) {
                int b = (r & 3) + 8 * (r >> 2) + 4 * half;
                float vv = vin[((size_t)o * B_ + b) * OD_ + d];
                bvp[r] = C[r] * vv;
            }
            #pragma unroll
            for (int m = 1; m <= 16; m <<= 1) {
                #pragma unroll
                for (int r = 0; r < 16; ++r)
                    bvp[r] += __shfl_xor(bvp[r], m, 32);
            }
            if ((lane & 31) == 0) {
                #pragma unroll
                for (int r = 0; r < 16; ++r) {
                    int b = (r & 3) + 8 * (r >> 2) + 4 * half;
                    blds[b * ON_ + o] = bvp[r];
                }
            }
        }
        __syncthreads();

        {
            int o = t & 63, bq = t >> 6;
            #pragma unroll
            for (int j = 0; j < 4; ++j) {
                int b = bq + 8 * j;
                float v = blds[b * ON_ + o];
                float m = v;
                #pragma unroll
                for (int mm = 1; mm <= 32; mm <<= 1) m = fmaxf(m, __shfl_xor(m, mm, 64));
                float e = __expf(v - m);
                float ssum = e;
                #pragma unroll
                for (int mm = 1; mm <= 32; mm <<= 1) ssum += __shfl_xor(ssum, mm, 64);
                clds[b * ON_ + o] = e / ssum;
            }
        }
        __syncthreads();

        #pragma unroll
        for (int oi = 0; oi < 8; ++oi) {
            int o = wv * 8 + oi;
            f32x16 z = {};
            f32x16 C = __builtin_amdgcn_mfma_f32_32x32x16_bf16(afr, bfr[oi], z, 0, 0, 0);
            #pragma unroll
            for (int r = 0; r < 16; ++r) {
                int b = (r & 3) + 8 * (r >> 2) + 4 * half;
                acc[oi][r] += clds[b * ON_ + o] * C[r];
            }
        }
        __syncthreads();
    }

    #pragma unroll
    for (int oi = 0; oi < 8; ++oi) {
        int o = wv * 8 + oi;
        #pragma unroll
        for (int r = 0; r < 16; ++r) {
            int b = (r & 3) + 8 * (r >> 2) + 4 * half;
            atomicAdd(&S[((size_t)b * ON_ + o) * OD_ + d], acc[oi][r]);
        }
    }
}

__global__ __launch_bounds__(256) void squash_k(
    const float* __restrict__ S, const float* __restrict__ addprev,
    float* __restrict__ out, float scale, int out_bod)
{
    int t = threadIdx.x;
    int row = blockIdx.x * 8 + (t >> 5);
    int d = t & 31;
    int b = row >> 6, o = row & 63;
    float s = S[(size_t)row * OD_ + d] * scale;
    float n2 = s * s;
    #pragma unroll
    for (int mm = 1; mm <= 16; mm <<= 1) n2 += __shfl_xor(n2, mm, 32);
    float norm = sqrtf(n2);
    float sc = n2 / ((1.0f + n2) * (norm + 1e-8f));
    float v = sc * s;
    if (addprev) v += addprev[((size_t)o * B_ + b) * OD_ + d];
    if (out_bod)
        out[((size_t)b * ON_ + o) * OD_ + d] = v;
    else
        out[((size_t)o * B_ + b) * OD_ + d] = v;
}

// ============================ LAUNCHER ======================================

extern "C" void kernel_launch(void* const* d_in, const int* in_sizes, int n_in,
                              void* d_out, int out_size, void* d_ws, size_t ws_size,
                              hipStream_t stream) {
    (void)in_sizes; (void)n_in; (void)out_size;
    const float* x = (const float*)d_in[0];
    const float* w = (const float*)d_in[1];
    float* out = (float*)d_out;

    const size_t WBF_B  = 134217728;   // 64*2048*1024
    const size_t XBF_B  = 2097152;     // 2048*1024
    const size_t PART_B = 16777216;    // 64*65536*4
    const size_t C_B    = 16777216;    // 2048*2048*4
    const size_t L_B    = 16777216;    // 2048*2048*4
    const size_t V_B    = 262144;
    const size_t NEED   = WBF_B + XBF_B + PART_B + C_B + L_B + 2 * V_B;

    if (ws_size >= NEED) {
        uint8_t* wsb = (uint8_t*)d_ws;
        uint4* wbf  = (uint4*)wsb;
        uint4* xbf  = (uint4*)(wsb + WBF_B);
        float* part = (float*)(wsb + WBF_B + XBF_B);
        float* c_g  = (float*)(wsb + WBF_B + XBF_B + PART_B);
        float* Lg   = (float*)(wsb + WBF_B + XBF_B + PART_B + C_B);
        float* v0   = (float*)(wsb + WBF_B + XBF_B + PART_B + C_B + L_B);
        float* vsum = (float*)(wsb + WBF_B + XBF_B + PART_B + C_B + L_B + V_B);

        xconv_k<<<512, 256, 0, stream>>>(x, xbf);
        pass0_k2<<<256, 1024, 0, stream>>>(w, xbf, wbf, part);
        reduce_squash_k<<<256, 256, 0, stream>>>(part, 64, 1.0f / 64.0f, nullptr, v0, 0);

        logits_raw_k<<<4096, 256, 0, stream>>>(wbf, xbf, v0, Lg);
        softmax_c_k<<<2048, 512, 0, stream>>>(Lg, c_g);
        accum_k<<<1024, 256, 0, stream>>>(wbf, xbf, c_g, part);
        reduce_squash_k<<<256, 256, 0, stream>>>(part, 64, 1.0f, v0, vsum, 0);

        logits_raw_k<<<4096, 256, 0, stream>>>(wbf, xbf, vsum, Lg);
        softmax_c_k<<<2048, 512, 0, stream>>>(Lg, c_g);
        accum_k<<<1024, 256, 0, stream>>>(wbf, xbf, c_g, part);
        reduce_squash_k<<<256, 256, 0, stream>>>(part, 64, 1.0f, nullptr, out, 1);
    } else {
        // legacy (round-1) path — needs only 768 KB of ws
        float* S    = (float*)d_ws;
        float* v0   = S + 65536;
        float* vsum = v0 + 65536;
        const size_t Sbytes = (size_t)65536 * sizeof(float);

        hipMemsetAsync(S, 0, Sbytes, stream);
        pass0_k<<<1024, 256, 0, stream>>>(x, w, S);
        squash_k<<<256, 256, 0, stream>>>(S, nullptr, v0, 1.0f / 64.0f, 0);

        hipMemsetAsync(S, 0, Sbytes, stream);
        pass_route_k<<<256, 512, 0, stream>>>(x, w, v0, S);
        squash_k<<<256, 256, 0, stream>>>(S, v0, vsum, 1.0f, 0);

        hipMemsetAsync(S, 0, Sbytes, stream);
        pass_route_k<<<256, 512, 0, stream>>>(x, w, vsum, S);
        squash_k<<<256, 256, 0, stream>>>(S, nullptr, out, 1.0f, 1);
    }
}

// Round 7
// 337.341 us; speedup vs baseline: 2.0266x; 1.0157x over previous
//
#include <hip/hip_runtime.h>
#include <cstdint>

typedef __attribute__((ext_vector_type(8))) short short8;
typedef __attribute__((ext_vector_type(16))) float f32x16;

#define B_   32
#define IN_  2048
#define ID_  16
#define ON_  64
#define OD_  32
// weight strides (floats): o: 1048576, i: 512, d: 16, k: 1

__device__ __forceinline__ unsigned short f2bf(float f) {
    union { float f; uint32_t u; } c; c.f = f;
    uint32_t u = c.u;
    uint32_t r = (u + 0x7FFFu + ((u >> 16) & 1u)) >> 16;
    return (unsigned short)r;
}
__device__ __forceinline__ unsigned int pack2(float a, float b) {
    return (unsigned int)f2bf(a) | ((unsigned int)f2bf(b) << 16);
}

// ============================ FAST PATH =====================================
// ws layout (bytes):
//   wbf  : bf16 weight, MFMA frag order, uint4[(o*2048+i)*64+lane]    134,217,728
//   xbf  : bf16 x, MFMA frag order, uint4[i*64+lane]                    2,097,152
//   part : fp32 partials [64][b*2048+o*32+d]                           16,777,216
//   c_g  : fp32 coupling coeffs [i][o][b]                              16,777,216
//   L    : fp32 raw logits [i][b][o]                                   16,777,216
//   v0, vsum : fp32 [o][b][d]                                             262,144 each
//
// Fragment symmetry note: per-lane data {elem j at (lane&31, k=(lane>>5)*8+j)}
// serves as BOTH the A-operand (m=lane&31) and B-operand (n=lane&31) of
// v_mfma_f32_32x32x16_bf16. So mfma(af,bb) gives xhat[b][d] and mfma(bb,af)
// gives xhat^T[d][b] with no re-layout.

// ---- pack x -> frag layout: lane holds x[b=lane&31, i, k=half*8+j] ---------
__global__ __launch_bounds__(256) void xconv_k(
    const float* __restrict__ x, uint4* __restrict__ xbf)
{
    int t = threadIdx.x, lane = t & 63, wv = t >> 6;
    int i = blockIdx.x * 4 + wv;
    int b = lane & 31, half = lane >> 5;
    const float* g = x + ((size_t)b * IN_ + i) * ID_ + half * 8;
    float4 a = *(const float4*)g;
    float4 c = *(const float4*)(g + 4);
    uint4 p = { pack2(a.x, a.y), pack2(a.z, a.w), pack2(c.x, c.y), pack2(c.z, c.w) };
    xbf[(size_t)i * 64 + lane] = p;
}

// ---- pass0: read w fp32 direct->reg, emit wbf, MFMA-accumulate S0 partials --
// grid 1024 = 16 og (4 o) x 64 ic (32 i). block 256 = 4 waves x 1 o.
// 256-thr blocks: finer scheduling granularity than the old 1024-thr version
// (up to 8 blocks/CU), same total 4096 waves.
__global__ __launch_bounds__(256) void pass0_k2(
    const float* __restrict__ w, const uint4* __restrict__ xbf,
    uint4* __restrict__ wbf, float* __restrict__ part)
{
    int t = threadIdx.x, lane = t & 63, wv = t >> 6;
    int og = blockIdx.x & 15, ic = blockIdx.x >> 4;
    int o = og * 4 + wv;
    int d = lane & 31, half = lane >> 5;

    f32x16 acc = {};
    #pragma unroll 4
    for (int ii = 0; ii < 32; ++ii) {
        int i = ic * 32 + ii;
        union { uint4 u; short8 s; } af;
        af.u = xbf[(size_t)i * 64 + lane];
        const float* g = w + ((size_t)o * IN_ + i) * 512 + d * 16 + half * 8;
        float4 a = *(const float4*)g;
        float4 c = *(const float4*)(g + 4);
        union { uint4 u; short8 s; } bf;
        bf.u = (uint4){ pack2(a.x, a.y), pack2(a.z, a.w), pack2(c.x, c.y), pack2(c.z, c.w) };
        wbf[((size_t)o * IN_ + i) * 64 + lane] = bf.u;
        acc = __builtin_amdgcn_mfma_f32_32x32x16_bf16(af.s, bf.s, acc, 0, 0, 0);
    }
    float* dst = part + (size_t)ic * 65536;
    #pragma unroll
    for (int r = 0; r < 16; ++r) {
        int b = (r & 3) + 8 * (r >> 2) + 4 * half;
        dst[(size_t)b * 2048 + o * 32 + d] = acc[r];
    }
}

// ---- raw logits via swapped-operand MFMA: in-lane dot, ONE shuffle ---------
// grid 4096 = (ic = bx>>6) x (o = bx&63). block 256 = 4 waves x 8 i.
// C2 = mfma(wbf, xbf) = xhat^T : col=lane&31=b, row d=(r&3)+8*(r>>2)+4*half.
// L[i][b][o] = sum_d v[o,b,d]*xhat[b,o,i,d] = in-lane 16-FMA + half-exchange.
__global__ __launch_bounds__(256, 4) void logits_raw_k(
    const uint4* __restrict__ wbf, const uint4* __restrict__ xbf,
    const float* __restrict__ vin /*[o][b][d]*/, float* __restrict__ L)
{
    int t = threadIdx.x, lane = t & 63, wv = t >> 6;
    int o = blockIdx.x & 63, ic = blockIdx.x >> 6;
    int b = lane & 31, half = lane >> 5;

    // hoist v for this o: lane needs v[o][b=lane&31][d(r,half)] for r=0..15
    float vr[16];
    #pragma unroll
    for (int r = 0; r < 16; ++r) {
        int d = (r & 3) + 8 * (r >> 2) + 4 * half;
        vr[r] = vin[(size_t)o * (B_ * OD_) + b * 32 + d];
    }

    #pragma unroll 4
    for (int ii = 0; ii < 8; ++ii) {
        int i = ic * 32 + wv * 8 + ii;
        union { uint4 u; short8 s; } af, bb;
        af.u = xbf[(size_t)i * 64 + lane];
        bb.u = wbf[((size_t)o * IN_ + i) * 64 + lane];
        f32x16 z = {};
        f32x16 C2 = __builtin_amdgcn_mfma_f32_32x32x16_bf16(bb.s, af.s, z, 0, 0, 0);
        float p0 = C2[0] * vr[0], p1 = C2[1] * vr[1];
        float p2 = C2[2] * vr[2], p3 = C2[3] * vr[3];
        #pragma unroll
        for (int r = 4; r < 16; r += 4) {
            p0 += C2[r + 0] * vr[r + 0];
            p1 += C2[r + 1] * vr[r + 1];
            p2 += C2[r + 2] * vr[r + 2];
            p3 += C2[r + 3] * vr[r + 3];
        }
        float partial = (p0 + p1) + (p2 + p3);
        float total = partial + __shfl_xor(partial, 32);   // add other-half d's
        if (half == 0)
            L[(size_t)i * 2048 + b * 64 + o] = total;
    }
}

// ---- softmax over o per (i,b): coalesced row read, shuffle softmax ---------
// grid 2048 (one i per block). block 512 = 8 waves; wave w, q: row b = w*4+q.
__global__ __launch_bounds__(512) void softmax_c_k(
    const float* __restrict__ L, float* __restrict__ c_g)
{
    int t = threadIdx.x, lane = t & 63, wv = t >> 6;
    int i = blockIdx.x;
    #pragma unroll
    for (int q = 0; q < 4; ++q) {
        int b = wv * 4 + q;
        float vl = L[(size_t)i * 2048 + b * 64 + lane];
        float m = vl;
        #pragma unroll
        for (int mm = 1; mm <= 32; mm <<= 1) m = fmaxf(m, __shfl_xor(m, mm, 64));
        float e = __expf(vl - m);
        float ss = e;
        #pragma unroll
        for (int mm = 1; mm <= 32; mm <<= 1) ss += __shfl_xor(ss, mm, 64);
        c_g[(size_t)i * 2048 + lane * 32 + b] = e / ss;
    }
}

// ---- accum: S partials = sum_i c[b,o,i] * xhat[b,o,i,:] --------------------
// grid 1024 = 16 ic x 64 o. block 256 = 4 waves, wave owns 32 i's. acc = 16 regs.
__global__ __launch_bounds__(256, 4) void accum_k(
    const uint4* __restrict__ wbf, const uint4* __restrict__ xbf,
    const float* __restrict__ c_g, float* __restrict__ part)
{
    int t = threadIdx.x, lane = t & 63, wv = t >> 6;
    int o = blockIdx.x & 63, ic = blockIdx.x >> 6;
    int d = lane & 31, half = lane >> 5;
    int i0 = ic * 128 + wv * 32;

    f32x16 acc = {};
    #pragma unroll 8
    for (int ii = 0; ii < 32; ++ii) {
        int i = i0 + ii;
        union { uint4 u; short8 s; } af;
        af.u = xbf[(size_t)i * 64 + lane];
        union { uint4 u; short8 s; } bb;
        bb.u = wbf[((size_t)o * IN_ + i) * 64 + lane];
        float cl = c_g[(size_t)i * 2048 + o * 32 + (lane & 31)];
        union { uint4 u; short8 s; } afs;
        #pragma unroll
        for (int j = 0; j < 4; ++j) {
            uint32_t p = ((const uint32_t*)&af.u)[j];
            union { float f; uint32_t u; } lo, hi;
            lo.u = (p & 0xFFFFu) << 16;
            hi.u = p & 0xFFFF0000u;
            ((uint32_t*)&afs.u)[j] = pack2(lo.f * cl, hi.f * cl);
        }
        acc = __builtin_amdgcn_mfma_f32_32x32x16_bf16(afs.s, bb.s, acc, 0, 0, 0);
    }

    float* dst = part + (size_t)(ic * 4 + wv) * 65536;
    #pragma unroll
    for (int r = 0; r < 16; ++r) {
        int b = (r & 3) + 8 * (r >> 2) + 4 * half;
        dst[(size_t)b * 2048 + o * 32 + d] = acc[r];
    }
}

// ---- reduce partials + squash (+optional add prev v) -----------------------
__global__ __launch_bounds__(256) void reduce_squash_k(
    const float* __restrict__ part, int nslices, float scale,
    const float* __restrict__ addprev, float* __restrict__ outv, int out_bod)
{
    int t = threadIdx.x, lane = t & 63, wv = t >> 6;
    int row = blockIdx.x * 8 + wv * 2 + (lane >> 5);
    int d = lane & 31;
    const float* p = part + (size_t)row * 32 + d;
    float s0 = 0, s1 = 0, s2 = 0, s3 = 0, s4 = 0, s5 = 0, s6 = 0, s7 = 0;
    for (int s = 0; s < nslices; s += 8) {
        s0 += p[(size_t)(s + 0) * 65536];
        s1 += p[(size_t)(s + 1) * 65536];
        s2 += p[(size_t)(s + 2) * 65536];
        s3 += p[(size_t)(s + 3) * 65536];
        s4 += p[(size_t)(s + 4) * 65536];
        s5 += p[(size_t)(s + 5) * 65536];
        s6 += p[(size_t)(s + 6) * 65536];
        s7 += p[(size_t)(s + 7) * 65536];
    }
    float sv = (((s0 + s1) + (s2 + s3)) + ((s4 + s5) + (s6 + s7))) * scale;
    float n2 = sv * sv;
    #pragma unroll
    for (int m = 1; m <= 16; m <<= 1) n2 += __shfl_xor(n2, m, 32);
    float norm = sqrtf(n2);
    float sc = n2 / ((1.0f + n2) * (norm + 1e-8f));
    float v = sc * sv;
    int b = row >> 6, o = row & 63;
    if (addprev) v += addprev[((size_t)o * B_ + b) * OD_ + d];
    if (out_bod) outv[(size_t)row * OD_ + d] = v;
    else         outv[((size_t)o * B_ + b) * OD_ + d] = v;
}

// ============================ LEGACY PATH (round-1, proven) =================

__global__ __launch_bounds__(256, 4) void pass0_k(
    const float* __restrict__ x, const float* __restrict__ w, float* __restrict__ S)
{
    __shared__ __align__(16) unsigned short lw[16 * 512];
    __shared__ __align__(16) unsigned short lx[512];

    const int t = threadIdx.x, lane = t & 63, wv = t >> 6;
    const int bx = blockIdx.x;
    const int ic = bx & 255, og = bx >> 8;
    const int o0 = og * 16;
    const int d = lane & 31, half = lane >> 5;

    f32x16 acc[4] = {};

    for (int i = ic * 8; i < ic * 8 + 8; ++i) {
        #pragma unroll
        for (int r = 0; r < 4; ++r) {
            int cidx = r * 256 + t;
            int ol = cidx >> 6, j8 = cidx & 63;
            const float* g = w + (size_t)(o0 + ol) * 1048576 + (size_t)i * 512 + j8 * 8;
            float4 a = *(const float4*)g;
            float4 b2 = *(const float4*)(g + 4);
            uint4 val = { pack2(a.x, a.y), pack2(a.z, a.w), pack2(b2.x, b2.y), pack2(b2.z, b2.w) };
            *reinterpret_cast<uint4*>(&lw[ol * 512 + j8 * 8]) = val;
        }
        if (t < 128) {
            int b = t >> 2, kq = t & 3;
            float4 a = *(const float4*)(x + ((size_t)b * IN_ + i) * ID_ + kq * 4);
            uint2 val = { pack2(a.x, a.y), pack2(a.z, a.w) };
            *reinterpret_cast<uint2*>(&lx[b * 16 + kq * 4]) = val;
        }
        __syncthreads();

        short8 afr = *reinterpret_cast<const short8*>(&lx[(lane & 31) * 16 + half * 8]);
        #pragma unroll
        for (int oi = 0; oi < 4; ++oi) {
            int ol = wv * 4 + oi;
            short8 bfr = *reinterpret_cast<const short8*>(&lw[ol * 512 + d * 16 + half * 8]);
            acc[oi] = __builtin_amdgcn_mfma_f32_32x32x16_bf16(afr, bfr, acc[oi], 0, 0, 0);
        }
        __syncthreads();
    }

    #pragma unroll
    for (int oi = 0; oi < 4; ++oi) {
        int o = o0 + wv * 4 + oi;
        #pragma unroll
        for (int r = 0; r < 16; ++r) {
            int b = (r & 3) + 8 * (r >> 2) + 4 * half;
            atomicAdd(&S[((size_t)b * ON_ + o) * OD_ + d], acc[oi][r]);
        }
    }
}

__global__ __launch_bounds__(512, 2) void pass_route_k(
    const float* __restrict__ x, const float* __restrict__ w,
    const float* __restrict__ vin, float* __restrict__ S)
{
    __shared__ __align__(16) unsigned short lw[64 * 512];
    __shared__ __align__(16) unsigned short lx[512];
    __shared__ float blds[B_ * ON_];
    __shared__ float clds[B_ * ON_];

    const int t = threadIdx.x, lane = t & 63, wv = t >> 6;
    const int ic = blockIdx.x;
    const int d = lane & 31, half = lane >> 5;

    f32x16 acc[8] = {};

    for (int i = ic * 8; i < ic * 8 + 8; ++i) {
        #pragma unroll
        for (int r = 0; r < 8; ++r) {
            int cidx = r * 512 + t;
            int ol = cidx >> 6, j8 = cidx & 63;
            const float* g = w + (size_t)ol * 1048576 + (size_t)i * 512 + j8 * 8;
            float4 a = *(const float4*)g;
            float4 b2 = *(const float4*)(g + 4);
            uint4 val = { pack2(a.x, a.y), pack2(a.z, a.w), pack2(b2.x, b2.y), pack2(b2.z, b2.w) };
            *reinterpret_cast<uint4*>(&lw[ol * 512 + j8 * 8]) = val;
        }
        if (t < 128) {
            int b = t >> 2, kq = t & 3;
            float4 a = *(const float4*)(x + ((size_t)b * IN_ + i) * ID_ + kq * 4);
            uint2 val = { pack2(a.x, a.y), pack2(a.z, a.w) };
            *reinterpret_cast<uint2*>(&lx[b * 16 + kq * 4]) = val;
        }
        __syncthreads();

        short8 afr = *reinterpret_cast<const short8*>(&lx[(lane & 31) * 16 + half * 8]);
        short8 bfr[8];

        #pragma unroll
        for (int oi = 0; oi < 8; ++oi) {
            int o = wv * 8 + oi;
            bfr[oi] = *reinterpret_cast<const short8*>(&lw[o * 512 + d * 16 + half * 8]);
            f32x16 z = {};
            f32x16 C = __builtin_amdgcn_mfma_f32_32x32x16_bf16(afr, bfr[oi], z, 0, 0, 0);
            float bvp[16];
            #pragma unroll
            for (int r = 0; r < 16; ++r) {
                int b = (r & 3) + 8 * (r >> 2) + 4 * half;
                float vv = vin[((size_t)o * B_ + b) * OD_ + d];
                bvp[r] = C[r] * vv;
            }
            #pragma unroll
            for (int m = 1; m <= 16; m <<= 1) {
                #pragma unroll
                for (int r = 0; r < 16; ++r)
                    bvp[r] += __shfl_xor(bvp[r], m, 32);
            }
            if ((lane & 31) == 0) {
                #pragma unroll
                for (int r = 0; r < 16; ++r) {
                    int b = (r & 3) + 8 * (r >> 2) + 4 * half;
                    blds[b * ON_ + o] = bvp[r];
                }
            }
        }
        __syncthreads();

        {
            int o = t & 63, bq = t >> 6;
            #pragma unroll
            for (int j = 0; j < 4; ++j) {
                int b = bq + 8 * j;
                float v = blds[b * ON_ + o];
                float m = v;
                #pragma unroll
                for (int mm = 1; mm <= 32; mm <<= 1) m = fmaxf(m, __shfl_xor(m, mm, 64));
                float e = __expf(v - m);
                float ssum = e;
                #pragma unroll
                for (int mm = 1; mm <= 32; mm <<= 1) ssum += __shfl_xor(ssum, mm, 64);
                clds[b * ON_ + o] = e / ssum;
            }
        }
        __syncthreads();

        #pragma unroll
        for (int oi = 0; oi < 8; ++oi) {
            int o = wv * 8 + oi;
            f32x16 z = {};
            f32x16 C = __builtin_amdgcn_mfma_f32_32x32x16_bf16(afr, bfr[oi], z, 0, 0, 0);
            #pragma unroll
            for (int r = 0; r < 16; ++r) {
                int b = (r & 3) + 8 * (r >> 2) + 4 * half;
                acc[oi][r] += clds[b * ON_ + o] * C[r];
            }
        }
        __syncthreads();
    }

    #pragma unroll
    for (int oi = 0; oi < 8; ++oi) {
        int o = wv * 8 + oi;
        #pragma unroll
        for (int r = 0; r < 16; ++r) {
            int b = (r & 3) + 8 * (r >> 2) + 4 * half;
            atomicAdd(&S[((size_t)b * ON_ + o) * OD_ + d], acc[oi][r]);
        }
    }
}

__global__ __launch_bounds__(256) void squash_k(
    const float* __restrict__ S, const float* __restrict__ addprev,
    float* __restrict__ out, float scale, int out_bod)
{
    int t = threadIdx.x;
    int row = blockIdx.x * 8 + (t >> 5);
    int d = t & 31;
    int b = row >> 6, o = row & 63;
    float s = S[(size_t)row * OD_ + d] * scale;
    float n2 = s * s;
    #pragma unroll
    for (int mm = 1; mm <= 16; mm <<= 1) n2 += __shfl_xor(n2, mm, 32);
    float norm = sqrtf(n2);
    float sc = n2 / ((1.0f + n2) * (norm + 1e-8f));
    float v = sc * s;
    if (addprev) v += addprev[((size_t)o * B_ + b) * OD_ + d];
    if (out_bod)
        out[((size_t)b * ON_ + o) * OD_ + d] = v;
    else
        out[((size_t)o * B_ + b) * OD_ + d] = v;
}

// ============================ LAUNCHER ======================================

extern "C" void kernel_launch(void* const* d_in, const int* in_sizes, int n_in,
                              void* d_out, int out_size, void* d_ws, size_t ws_size,
                              hipStream_t stream) {
    (void)in_sizes; (void)n_in; (void)out_size;
    const float* x = (const float*)d_in[0];
    const float* w = (const float*)d_in[1];
    float* out = (float*)d_out;

    const size_t WBF_B  = 134217728;   // 64*2048*1024
    const size_t XBF_B  = 2097152;     // 2048*1024
    const size_t PART_B = 16777216;    // 64*65536*4
    const size_t C_B    = 16777216;    // 2048*2048*4
    const size_t L_B    = 16777216;    // 2048*2048*4
    const size_t V_B    = 262144;
    const size_t NEED   = WBF_B + XBF_B + PART_B + C_B + L_B + 2 * V_B;

    if (ws_size >= NEED) {
        uint8_t* wsb = (uint8_t*)d_ws;
        uint4* wbf  = (uint4*)wsb;
        uint4* xbf  = (uint4*)(wsb + WBF_B);
        float* part = (float*)(wsb + WBF_B + XBF_B);
        float* c_g  = (float*)(wsb + WBF_B + XBF_B + PART_B);
        float* Lg   = (float*)(wsb + WBF_B + XBF_B + PART_B + C_B);
        float* v0   = (float*)(wsb + WBF_B + XBF_B + PART_B + C_B + L_B);
        float* vsum = (float*)(wsb + WBF_B + XBF_B + PART_B + C_B + L_B + V_B);

        xconv_k<<<512, 256, 0, stream>>>(x, xbf);
        pass0_k2<<<1024, 256, 0, stream>>>(w, xbf, wbf, part);
        reduce_squash_k<<<256, 256, 0, stream>>>(part, 64, 1.0f / 64.0f, nullptr, v0, 0);

        logits_raw_k<<<4096, 256, 0, stream>>>(wbf, xbf, v0, Lg);
        softmax_c_k<<<2048, 512, 0, stream>>>(Lg, c_g);
        accum_k<<<1024, 256, 0, stream>>>(wbf, xbf, c_g, part);
        reduce_squash_k<<<256, 256, 0, stream>>>(part, 64, 1.0f, v0, vsum, 0);

        logits_raw_k<<<4096, 256, 0, stream>>>(wbf, xbf, vsum, Lg);
        softmax_c_k<<<2048, 512, 0, stream>>>(Lg, c_g);
        accum_k<<<1024, 256, 0, stream>>>(wbf, xbf, c_g, part);
        reduce_squash_k<<<256, 256, 0, stream>>>(part, 64, 1.0f, nullptr, out, 1);
    } else {
        // legacy (round-1) path — needs only 768 KB of ws
        float* S    = (float*)d_ws;
        float* v0   = S + 65536;
        float* vsum = v0 + 65536;
        const size_t Sbytes = (size_t)65536 * sizeof(float);

        hipMemsetAsync(S, 0, Sbytes, stream);
        pass0_k<<<1024, 256, 0, stream>>>(x, w, S);
        squash_k<<<256, 256, 0, stream>>>(S, nullptr, v0, 1.0f / 64.0f, 0);

        hipMemsetAsync(S, 0, Sbytes, stream);
        pass_route_k<<<256, 512, 0, stream>>>(x, w, v0, S);
        squash_k<<<256, 256, 0, stream>>>(S, v0, vsum, 1.0f, 0);

        hipMemsetAsync(S, 0, Sbytes, stream);
        pass_route_k<<<256, 512, 0, stream>>>(x, w, vsum, S);
        squash_k<<<256, 256, 0, stream>>>(S, nullptr, out, 1.0f, 1);
    }
}

// Round 8
// 251.732 us; speedup vs baseline: 2.7158x; 1.3401x over previous
//
#include <hip/hip_runtime.h>
#include <cstdint>

typedef __attribute__((ext_vector_type(8))) short short8;
typedef __attribute__((ext_vector_type(16))) float f32x16;

#define B_   32
#define IN_  2048
#define ID_  16
#define ON_  64
#define OD_  32
// weight strides (floats): o: 1048576, i: 512, d: 16, k: 1

__device__ __forceinline__ unsigned short f2bf(float f) {
    union { float f; uint32_t u; } c; c.f = f;
    uint32_t u = c.u;
    uint32_t r = (u + 0x7FFFu + ((u >> 16) & 1u)) >> 16;
    return (unsigned short)r;
}
__device__ __forceinline__ unsigned int pack2(float a, float b) {
    return (unsigned int)f2bf(a) | ((unsigned int)f2bf(b) << 16);
}

// ============================ FAST PATH =====================================
// ws layout (bytes):
//   wbf  : bf16 weight, MFMA frag order, uint4[(o*2048+i)*64+lane]    134,217,728
//   xbf  : bf16 x, MFMA frag order, uint4[i*64+lane]                    2,097,152
//   part : fp32 partials [64][b*2048+o*32+d]                           16,777,216
//   L    : fp32 raw logits [i][o][b]  (COALESCED layout)               16,777,216
//   msum : fp32 [i][ {m[32], rinv[32]} ]                                  524,288
//   v0, vsum : fp32 [o][b][d]                                             262,144 each
//
// Fragment symmetry: per-lane data {elem j at (lane&31, k=(lane>>5)*8+j)}
// serves as BOTH A-operand (m=lane&31) and B-operand (n=lane&31) of
// v_mfma_f32_32x32x16_bf16. mfma(af,bb) -> xhat[b][d]; mfma(bb,af) -> xhat^T[d][b].

// ---- pack x -> frag layout: lane holds x[b=lane&31, i, k=half*8+j] ---------
__global__ __launch_bounds__(256) void xconv_k(
    const float* __restrict__ x, uint4* __restrict__ xbf)
{
    int t = threadIdx.x, lane = t & 63, wv = t >> 6;
    int i = blockIdx.x * 4 + wv;
    int b = lane & 31, half = lane >> 5;
    const float* g = x + ((size_t)b * IN_ + i) * ID_ + half * 8;
    float4 a = *(const float4*)g;
    float4 c = *(const float4*)(g + 4);
    uint4 p = { pack2(a.x, a.y), pack2(a.z, a.w), pack2(c.x, c.y), pack2(c.z, c.w) };
    xbf[(size_t)i * 64 + lane] = p;
}

// ---- pass0: read w fp32 direct->reg, emit wbf, MFMA-accumulate S0 partials --
// grid 1024 = 16 og (4 o) x 64 ic (32 i). block 256 = 4 waves x 1 o.
__global__ __launch_bounds__(256) void pass0_k2(
    const float* __restrict__ w, const uint4* __restrict__ xbf,
    uint4* __restrict__ wbf, float* __restrict__ part)
{
    int t = threadIdx.x, lane = t & 63, wv = t >> 6;
    int og = blockIdx.x & 15, ic = blockIdx.x >> 4;
    int o = og * 4 + wv;
    int d = lane & 31, half = lane >> 5;

    f32x16 acc = {};
    #pragma unroll 4
    for (int ii = 0; ii < 32; ++ii) {
        int i = ic * 32 + ii;
        union { uint4 u; short8 s; } af;
        af.u = xbf[(size_t)i * 64 + lane];
        const float* g = w + ((size_t)o * IN_ + i) * 512 + d * 16 + half * 8;
        float4 a = *(const float4*)g;
        float4 c = *(const float4*)(g + 4);
        union { uint4 u; short8 s; } bf;
        bf.u = (uint4){ pack2(a.x, a.y), pack2(a.z, a.w), pack2(c.x, c.y), pack2(c.z, c.w) };
        wbf[((size_t)o * IN_ + i) * 64 + lane] = bf.u;
        acc = __builtin_amdgcn_mfma_f32_32x32x16_bf16(af.s, bf.s, acc, 0, 0, 0);
    }
    float* dst = part + (size_t)ic * 65536;
    #pragma unroll
    for (int r = 0; r < 16; ++r) {
        int b = (r & 3) + 8 * (r >> 2) + 4 * half;
        dst[(size_t)b * 2048 + o * 32 + d] = acc[r];
    }
}

// ---- raw logits via swapped-operand MFMA; COALESCED L[i][o][b] store -------
// grid 4096 = (ic = bx>>6) x (o = bx&63). block 256 = 4 waves x 8 i.
__global__ __launch_bounds__(256, 4) void logits_raw_k(
    const uint4* __restrict__ wbf, const uint4* __restrict__ xbf,
    const float* __restrict__ vin /*[o][b][d]*/, float* __restrict__ L)
{
    int t = threadIdx.x, lane = t & 63, wv = t >> 6;
    int o = blockIdx.x & 63, ic = blockIdx.x >> 6;
    int b = lane & 31, half = lane >> 5;

    // hoist v for this o: lane needs v[o][b=lane&31][d(r,half)] for r=0..15
    float vr[16];
    #pragma unroll
    for (int r = 0; r < 16; ++r) {
        int d = (r & 3) + 8 * (r >> 2) + 4 * half;
        vr[r] = vin[(size_t)o * (B_ * OD_) + b * 32 + d];
    }

    #pragma unroll 8
    for (int ii = 0; ii < 8; ++ii) {
        int i = ic * 32 + wv * 8 + ii;
        union { uint4 u; short8 s; } af, bb;
        af.u = xbf[(size_t)i * 64 + lane];
        bb.u = wbf[((size_t)o * IN_ + i) * 64 + lane];
        f32x16 z = {};
        f32x16 C2 = __builtin_amdgcn_mfma_f32_32x32x16_bf16(bb.s, af.s, z, 0, 0, 0);
        float p0 = C2[0] * vr[0], p1 = C2[1] * vr[1];
        float p2 = C2[2] * vr[2], p3 = C2[3] * vr[3];
        #pragma unroll
        for (int r = 4; r < 16; r += 4) {
            p0 += C2[r + 0] * vr[r + 0];
            p1 += C2[r + 1] * vr[r + 1];
            p2 += C2[r + 2] * vr[r + 2];
            p3 += C2[r + 3] * vr[r + 3];
        }
        float partial = (p0 + p1) + (p2 + p3);
        float total = partial + __shfl_xor(partial, 32);   // add other-half d's
        if (half == 0)
            L[((size_t)i * 64 + o) * 32 + b] = total;      // 128 B coalesced
    }
}

// ---- per-(i,b) softmax stats over o: m and 1/sum (tiny output) -------------
// grid 512, block 256 = 4 waves, one i per wave. LDS 32 KB -> coalesced read.
__global__ __launch_bounds__(256) void msum_k(
    const float* __restrict__ L, float* __restrict__ msum /*[i][64]: m|rinv*/)
{
    __shared__ float sl[4][2048];
    int t = threadIdx.x, lane = t & 63, wv = t >> 6;
    int i = blockIdx.x * 4 + wv;
    const float4* src4 = reinterpret_cast<const float4*>(L + (size_t)i * 2048);
    float4* dst4 = reinterpret_cast<float4*>(sl[wv]);
    #pragma unroll
    for (int j = 0; j < 8; ++j) dst4[j * 64 + lane] = src4[j * 64 + lane];
    // same-wave LDS write->read: hardware-ordered via lgkmcnt, no barrier.
    int b = lane & 31, half = lane >> 5;
    float m = -1e30f;
    #pragma unroll
    for (int o = 0; o < 32; ++o)
        m = fmaxf(m, sl[wv][(half * 32 + o) * 32 + b]);   // bank=b, 2-way: free
    m = fmaxf(m, __shfl_xor(m, 32));
    float s = 0.0f;
    #pragma unroll
    for (int o = 0; o < 32; ++o)
        s += __expf(sl[wv][(half * 32 + o) * 32 + b] - m);
    s += __shfl_xor(s, 32);
    if (half == 0) {
        msum[(size_t)i * 64 + b]      = m;
        msum[(size_t)i * 64 + 32 + b] = 1.0f / s;
    }
}

// ---- accum: S partials = sum_i c * xhat, c = exp(L-m)*rinv computed inline -
// grid 1024 = 16 ic x 64 o. block 256 = 4 waves, wave owns 32 i's. acc = 16 regs.
__global__ __launch_bounds__(256, 4) void accum_k(
    const uint4* __restrict__ wbf, const uint4* __restrict__ xbf,
    const float* __restrict__ L, const float* __restrict__ msum,
    float* __restrict__ part)
{
    int t = threadIdx.x, lane = t & 63, wv = t >> 6;
    int o = blockIdx.x & 63, ic = blockIdx.x >> 6;
    int d = lane & 31, half = lane >> 5;
    int b = lane & 31;
    int i0 = ic * 128 + wv * 32;

    f32x16 acc = {};
    #pragma unroll 8
    for (int ii = 0; ii < 32; ++ii) {
        int i = i0 + ii;
        union { uint4 u; short8 s; } af;
        af.u = xbf[(size_t)i * 64 + lane];
        union { uint4 u; short8 s; } bb;
        bb.u = wbf[((size_t)o * IN_ + i) * 64 + lane];
        float Lv   = L[((size_t)i * 64 + o) * 32 + b];
        float mv   = msum[(size_t)i * 64 + b];
        float rinv = msum[(size_t)i * 64 + 32 + b];
        float cl = __expf(Lv - mv) * rinv;
        union { uint4 u; short8 s; } afs;
        #pragma unroll
        for (int j = 0; j < 4; ++j) {
            uint32_t p = ((const uint32_t*)&af.u)[j];
            union { float f; uint32_t u; } lo, hi;
            lo.u = (p & 0xFFFFu) << 16;
            hi.u = p & 0xFFFF0000u;
            ((uint32_t*)&afs.u)[j] = pack2(lo.f * cl, hi.f * cl);
        }
        acc = __builtin_amdgcn_mfma_f32_32x32x16_bf16(afs.s, bb.s, acc, 0, 0, 0);
    }

    float* dst = part + (size_t)(ic * 4 + wv) * 65536;
    #pragma unroll
    for (int r = 0; r < 16; ++r) {
        int bb2 = (r & 3) + 8 * (r >> 2) + 4 * half;
        dst[(size_t)bb2 * 2048 + o * 32 + d] = acc[r];
    }
}

// ---- reduce partials + squash (+optional add prev v) -----------------------
__global__ __launch_bounds__(256) void reduce_squash_k(
    const float* __restrict__ part, int nslices, float scale,
    const float* __restrict__ addprev, float* __restrict__ outv, int out_bod)
{
    int t = threadIdx.x, lane = t & 63, wv = t >> 6;
    int row = blockIdx.x * 8 + wv * 2 + (lane >> 5);
    int d = lane & 31;
    const float* p = part + (size_t)row * 32 + d;
    float s0 = 0, s1 = 0, s2 = 0, s3 = 0, s4 = 0, s5 = 0, s6 = 0, s7 = 0;
    for (int s = 0; s < nslices; s += 8) {
        s0 += p[(size_t)(s + 0) * 65536];
        s1 += p[(size_t)(s + 1) * 65536];
        s2 += p[(size_t)(s + 2) * 65536];
        s3 += p[(size_t)(s + 3) * 65536];
        s4 += p[(size_t)(s + 4) * 65536];
        s5 += p[(size_t)(s + 5) * 65536];
        s6 += p[(size_t)(s + 6) * 65536];
        s7 += p[(size_t)(s + 7) * 65536];
    }
    float sv = (((s0 + s1) + (s2 + s3)) + ((s4 + s5) + (s6 + s7))) * scale;
    float n2 = sv * sv;
    #pragma unroll
    for (int m = 1; m <= 16; m <<= 1) n2 += __shfl_xor(n2, m, 32);
    float norm = sqrtf(n2);
    float sc = n2 / ((1.0f + n2) * (norm + 1e-8f));
    float v = sc * sv;
    int b = row >> 6, o = row & 63;
    if (addprev) v += addprev[((size_t)o * B_ + b) * OD_ + d];
    if (out_bod) outv[(size_t)row * OD_ + d] = v;
    else         outv[((size_t)o * B_ + b) * OD_ + d] = v;
}

// ============================ LEGACY PATH (round-1, proven) =================

__global__ __launch_bounds__(256, 4) void pass0_k(
    const float* __restrict__ x, const float* __restrict__ w, float* __restrict__ S)
{
    __shared__ __align__(16) unsigned short lw[16 * 512];
    __shared__ __align__(16) unsigned short lx[512];

    const int t = threadIdx.x, lane = t & 63, wv = t >> 6;
    const int bx = blockIdx.x;
    const int ic = bx & 255, og = bx >> 8;
    const int o0 = og * 16;
    const int d = lane & 31, half = lane >> 5;

    f32x16 acc[4] = {};

    for (int i = ic * 8; i < ic * 8 + 8; ++i) {
        #pragma unroll
        for (int r = 0; r < 4; ++r) {
            int cidx = r * 256 + t;
            int ol = cidx >> 6, j8 = cidx & 63;
            const float* g = w + (size_t)(o0 + ol) * 1048576 + (size_t)i * 512 + j8 * 8;
            float4 a = *(const float4*)g;
            float4 b2 = *(const float4*)(g + 4);
            uint4 val = { pack2(a.x, a.y), pack2(a.z, a.w), pack2(b2.x, b2.y), pack2(b2.z, b2.w) };
            *reinterpret_cast<uint4*>(&lw[ol * 512 + j8 * 8]) = val;
        }
        if (t < 128) {
            int b = t >> 2, kq = t & 3;
            float4 a = *(const float4*)(x + ((size_t)b * IN_ + i) * ID_ + kq * 4);
            uint2 val = { pack2(a.x, a.y), pack2(a.z, a.w) };
            *reinterpret_cast<uint2*>(&lx[b * 16 + kq * 4]) = val;
        }
        __syncthreads();

        short8 afr = *reinterpret_cast<const short8*>(&lx[(lane & 31) * 16 + half * 8]);
        #pragma unroll
        for (int oi = 0; oi < 4; ++oi) {
            int ol = wv * 4 + oi;
            short8 bfr = *reinterpret_cast<const short8*>(&lw[ol * 512 + d * 16 + half * 8]);
            acc[oi] = __builtin_amdgcn_mfma_f32_32x32x16_bf16(afr, bfr, acc[oi], 0, 0, 0);
        }
        __syncthreads();
    }

    #pragma unroll
    for (int oi = 0; oi < 4; ++oi) {
        int o = o0 + wv * 4 + oi;
        #pragma unroll
        for (int r = 0; r < 16; ++r) {
            int b = (r & 3) + 8 * (r >> 2) + 4 * half;
            atomicAdd(&S[((size_t)b * ON_ + o) * OD_ + d], acc[oi][r]);
        }
    }
}

__global__ __launch_bounds__(512, 2) void pass_route_k(
    const float* __restrict__ x, const float* __restrict__ w,
    const float* __restrict__ vin, float* __restrict__ S)
{
    __shared__ __align__(16) unsigned short lw[64 * 512];
    __shared__ __align__(16) unsigned short lx[512];
    __shared__ float blds[B_ * ON_];
    __shared__ float clds[B_ * ON_];

    const int t = threadIdx.x, lane = t & 63, wv = t >> 6;
    const int ic = blockIdx.x;
    const int d = lane & 31, half = lane >> 5;

    f32x16 acc[8] = {};

    for (int i = ic * 8; i < ic * 8 + 8; ++i) {
        #pragma unroll
        for (int r = 0; r < 8; ++r) {
            int cidx = r * 512 + t;
            int ol = cidx >> 6, j8 = cidx & 63;
            const float* g = w + (size_t)ol * 1048576 + (size_t)i * 512 + j8 * 8;
            float4 a = *(const float4*)g;
            float4 b2 = *(const float4*)(g + 4);
            uint4 val = { pack2(a.x, a.y), pack2(a.z, a.w), pack2(b2.x, b2.y), pack2(b2.z, b2.w) };
            *reinterpret_cast<uint4*>(&lw[ol * 512 + j8 * 8]) = val;
        }
        if (t < 128) {
            int b = t >> 2, kq = t & 3;
            float4 a = *(const float4*)(x + ((size_t)b * IN_ + i) * ID_ + kq * 4);
            uint2 val = { pack2(a.x, a.y), pack2(a.z, a.w) };
            *reinterpret_cast<uint2*>(&lx[b * 16 + kq * 4]) = val;
        }
        __syncthreads();

        short8 afr = *reinterpret_cast<const short8*>(&lx[(lane & 31) * 16 + half * 8]);
        short8 bfr[8];

        #pragma unroll
        for (int oi = 0; oi < 8; ++oi) {
            int o = wv * 8 + oi;
            bfr[oi] = *reinterpret_cast<const short8*>(&lw[o * 512 + d * 16 + half * 8]);
            f32x16 z = {};
            f32x16 C = __builtin_amdgcn_mfma_f32_32x32x16_bf16(afr, bfr[oi], z, 0, 0, 0);
            float bvp[16];
            #pragma unroll
            for (int r = 0; r < 16; ++r) {
                int b = (r & 3) + 8 * (r >> 2) + 4 * half;
                float vv = vin[((size_t)o * B_ + b) * OD_ + d];
                bvp[r] = C[r] * vv;
            }
            #pragma unroll
            for (int m = 1; m <= 16; m <<= 1) {
                #pragma unroll
                for (int r = 0; r < 16; ++r)
                    bvp[r] += __shfl_xor(bvp[r], m, 32);
            }
            if ((lane & 31) == 0) {
                #pragma unroll
                for (int r = 0; r < 16; ++r) {
                    int b = (r & 3) + 8 * (r >> 2) + 4 * half;
                    blds[b * ON_ + o] = bvp[r];
                }
            }
        }
        __syncthreads();

        {
            int o = t & 63, bq = t >> 6;
            #pragma unroll
            for (int j = 0; j < 4; ++j) {
                int b = bq + 8 * j;
                float v = blds[b * ON_ + o];
                float m = v;
                #pragma unroll
                for (int mm = 1; mm <= 32; mm <<= 1) m = fmaxf(m, __shfl_xor(m, mm, 64));
                float e = __expf(v - m);
                float ssum = e;
                #pragma unroll
                for (int mm = 1; mm <= 32; mm <<= 1) ssum += __shfl_xor(ssum, mm, 64);
                clds[b * ON_ + o] = e / ssum;
            }
        }
        __syncthreads();

        #pragma unroll
        for (int oi = 0; oi < 8; ++oi) {
            int o = wv * 8 + oi;
            f32x16 z = {};
            f32x16 C = __builtin_amdgcn_mfma_f32_32x32x16_bf16(afr, bfr[oi], z, 0, 0, 0);
            #pragma unroll
            for (int r = 0; r < 16; ++r) {
                int b = (r & 3) + 8 * (r >> 2) + 4 * half;
                acc[oi][r] += clds[b * ON_ + o] * C[r];
            }
        }
        __syncthreads();
    }

    #pragma unroll
    for (int oi = 0; oi < 8; ++oi) {
        int o = wv * 8 + oi;
        #pragma unroll
        for (int r = 0; r < 16; ++r) {
            int b = (r & 3) + 8 * (r >> 2) + 4 * half;
            atomicAdd(&S[((size_t)b * ON_ + o) * OD_ + d], acc[oi][r]);
        }
    }
}

__global__ __launch_bounds__(256) void squash_k(
    const float* __restrict__ S, const float* __restrict__ addprev,
    float* __restrict__ out, float scale, int out_bod)
{
    int t = threadIdx.x;
    int row = blockIdx.x * 8 + (t >> 5);
    int d = t & 31;
    int b = row >> 6, o = row & 63;
    float s = S[(size_t)row * OD_ + d] * scale;
    float n2 = s * s;
    #pragma unroll
    for (int mm = 1; mm <= 16; mm <<= 1) n2 += __shfl_xor(n2, mm, 32);
    float norm = sqrtf(n2);
    float sc = n2 / ((1.0f + n2) * (norm + 1e-8f));
    float v = sc * s;
    if (addprev) v += addprev[((size_t)o * B_ + b) * OD_ + d];
    if (out_bod)
        out[((size_t)b * ON_ + o) * OD_ + d] = v;
    else
        out[((size_t)o * B_ + b) * OD_ + d] = v;
}

// ============================ LAUNCHER ======================================

extern "C" void kernel_launch(void* const* d_in, const int* in_sizes, int n_in,
                              void* d_out, int out_size, void* d_ws, size_t ws_size,
                              hipStream_t stream) {
    (void)in_sizes; (void)n_in; (void)out_size;
    const float* x = (const float*)d_in[0];
    const float* w = (const float*)d_in[1];
    float* out = (float*)d_out;

    const size_t WBF_B  = 134217728;   // 64*2048*1024
    const size_t XBF_B  = 2097152;     // 2048*1024
    const size_t PART_B = 16777216;    // 64*65536*4
    const size_t L_B    = 16777216;    // 2048*2048*4
    const size_t MS_B   = 524288;      // 2048*64*4
    const size_t V_B    = 262144;
    const size_t NEED   = WBF_B + XBF_B + PART_B + L_B + MS_B + 2 * V_B;

    if (ws_size >= NEED) {
        uint8_t* wsb = (uint8_t*)d_ws;
        uint4* wbf  = (uint4*)wsb;
        uint4* xbf  = (uint4*)(wsb + WBF_B);
        float* part = (float*)(wsb + WBF_B + XBF_B);
        float* Lg   = (float*)(wsb + WBF_B + XBF_B + PART_B);
        float* ms   = (float*)(wsb + WBF_B + XBF_B + PART_B + L_B);
        float* v0   = (float*)(wsb + WBF_B + XBF_B + PART_B + L_B + MS_B);
        float* vsum = (float*)(wsb + WBF_B + XBF_B + PART_B + L_B + MS_B + V_B);

        xconv_k<<<512, 256, 0, stream>>>(x, xbf);
        pass0_k2<<<1024, 256, 0, stream>>>(w, xbf, wbf, part);
        reduce_squash_k<<<256, 256, 0, stream>>>(part, 64, 1.0f / 64.0f, nullptr, v0, 0);

        logits_raw_k<<<4096, 256, 0, stream>>>(wbf, xbf, v0, Lg);
        msum_k<<<512, 256, 0, stream>>>(Lg, ms);
        accum_k<<<1024, 256, 0, stream>>>(wbf, xbf, Lg, ms, part);
        reduce_squash_k<<<256, 256, 0, stream>>>(part, 64, 1.0f, v0, vsum, 0);

        logits_raw_k<<<4096, 256, 0, stream>>>(wbf, xbf, vsum, Lg);
        msum_k<<<512, 256, 0, stream>>>(Lg, ms);
        accum_k<<<1024, 256, 0, stream>>>(wbf, xbf, Lg, ms, part);
        reduce_squash_k<<<256, 256, 0, stream>>>(part, 64, 1.0f, nullptr, out, 1);
    } else {
        // legacy (round-1) path — needs only 768 KB of ws
        float* S    = (float*)d_ws;
        float* v0   = S + 65536;
        float* vsum = v0 + 65536;
        const size_t Sbytes = (size_t)65536 * sizeof(float);

        hipMemsetAsync(S, 0, Sbytes, stream);
        pass0_k<<<1024, 256, 0, stream>>>(x, w, S);
        squash_k<<<256, 256, 0, stream>>>(S, nullptr, v0, 1.0f / 64.0f, 0);

        hipMemsetAsync(S, 0, Sbytes, stream);
        pass_route_k<<<256, 512, 0, stream>>>(x, w, v0, S);
        squash_k<<<256, 256, 0, stream>>>(S, v0, vsum, 1.0f, 0);

        hipMemsetAsync(S, 0, Sbytes, stream);
        pass_route_k<<<256, 512, 0, stream>>>(x, w, vsum, S);
        squash_k<<<256, 256, 0, stream>>>(S, nullptr, out, 1.0f, 1);
    }
}